// Round 10
// baseline (4963.254 us; speedup 1.0000x reference)
//
#include <hip/hip_runtime.h>
#include <hip/hip_bf16.h>
#include <stdint.h>

#define B 8
#define NN 16383
#define INDIM 300
#define HDIM 512
#define EDIM 100

typedef short bf16x8 __attribute__((ext_vector_type(8)));
typedef float f32x4 __attribute__((ext_vector_type(4)));
typedef unsigned short ushort_t;

__device__ __forceinline__ float sigmoidf_(float v) { return 1.0f / (1.0f + __expf(-v)); }

__device__ __forceinline__ ushort_t f2b(float f) {
    union { float f; unsigned int u; } x; x.f = f;
    unsigned int u = x.u;
    return (ushort_t)((u + 0x7FFFu + ((u >> 16) & 1u)) >> 16);
}
__device__ __forceinline__ float b2f(ushort_t s) {
    union { float f; unsigned int u; } x; x.u = ((unsigned int)s) << 16; return x.f;
}
__device__ __forceinline__ bf16x8 zero8() {
    bf16x8 v;
#pragma unroll
    for (int i = 0; i < 8; ++i) v[i] = 0;
    return v;
}

// packed h/c layout (K=512): elem (R, col) ->
//   (R>>4)*8192 + (col>>5)*512 + ((col>>3)&3)*128 + (R&15)*8 + (col&7)
__device__ __forceinline__ unsigned int pidx(int R, int col) {
    return (unsigned int)((R >> 4) * 8192 + (col >> 5) * 512 + ((col >> 3) & 3) * 128
                          + (R & 15) * 8 + (col & 7));
}

// swizzled LDS xs (stride 320 ushorts = 640B), frag read 16B
__device__ __forceinline__ bf16x8 xs_frag(const ushort_t* xs, int row, int kt, int kr) {
    unsigned int byte = (unsigned int)(row * 640 + kt * 64 + kr * 16) ^ (unsigned int)((row & 7) << 4);
    return *reinterpret_cast<const bf16x8*>(reinterpret_cast<const char*>(xs) + byte);
}
// swizzled LDS, generic stride (bytes), 16B frag read / 2B store
__device__ __forceinline__ bf16x8 sw_frag(const ushort_t* buf, int row, int lc_bytes, int stride) {
    unsigned int byte = (unsigned int)(row * stride + lc_bytes) ^ (unsigned int)((row & 7) << 4);
    return *reinterpret_cast<const bf16x8*>(reinterpret_cast<const char*>(buf) + byte);
}
__device__ __forceinline__ void sw_store2(ushort_t* buf, int row, int lc, ushort_t v, int stride) {
    unsigned int byte = (unsigned int)(row * stride + lc * 2) ^ (unsigned int)((row & 7) << 4);
    *reinterpret_cast<ushort_t*>(reinterpret_cast<char*>(buf) + byte) = v;
}

// ---------------- pack weights into MFMA B-fragment order.
__global__ __launch_bounds__(256) void pack_kernel(
    const float* __restrict__ W, ushort_t* __restrict__ out,
    int Kdim, int Kt, int total)
{
    int idx = blockIdx.x * 256 + threadIdx.x;
    if (idx >= total) return;
    int lane = idx & 63;
    int kt = (idx >> 6) % Kt;
    int nt = idx / (Kt << 6);
    int n = nt * 16 + (lane & 15);
    int kb = kt * 32 + (lane >> 4) * 8;
    ushort_t v[8];
#pragma unroll
    for (int i = 0; i < 8; ++i) {
        int k = kb + i;
        v[i] = (k < Kdim) ? f2b(W[(size_t)n * Kdim + k]) : (ushort_t)0;
    }
    *reinterpret_cast<uint4*>(out + (size_t)idx * 8) = *reinterpret_cast<const uint4*>(v);
}

// ---------------- children v5: 4 parents/block; 52KB LDS, 3 blocks/CU, A-preload.
__global__ __launch_bounds__(256, 3) void children_kernel(
    const float* __restrict__ inputs, const float* __restrict__ edge_inputs,
    const ushort_t* __restrict__ pWfx, const float* __restrict__ bfx,
    const ushort_t* __restrict__ pWfh, const float* __restrict__ bfh,
    const ushort_t* __restrict__ pWe,  const float* __restrict__ be,
    const ushort_t* __restrict__ hX, const ushort_t* __restrict__ cX,
    ushort_t* __restrict__ hY, ushort_t* __restrict__ cY,
    int start, int n)
{
    const int nb = blockIdx.x * 4;
    const int t = threadIdx.x;
    const int w = t >> 6, lane = t & 63;
    const int kr = lane >> 4, cl = lane & 15;

    __shared__ ushort_t xs[32 * 320];   // 20 KB swizzled (stride 640B)
    __shared__ ushort_t wc[64 * 128];   // 16 KB swizzled (stride 256B)
    __shared__ ushort_t epi[64 * 128];  // 16 KB swizzled (stride 256B), half-width plane

    // stage x (rows p*8+b, 4 parents)
    for (int i = t; i < 32 * 80; i += 256) {
        int r = i / 80, ch = i - r * 80;
        int p = r >> 3, b = r & 7, k = ch * 4;
        ushort_t vv[4] = {0, 0, 0, 0};
        if (k < INDIM && (nb + p) < n) {
            float4 xv = *reinterpret_cast<const float4*>(
                &inputs[((size_t)b * NN + start + nb + p) * INDIM + k]);
            vv[0] = f2b(xv.x); vv[1] = f2b(xv.y); vv[2] = f2b(xv.z); vv[3] = f2b(xv.w);
        }
        unsigned int byte = (unsigned int)(r * 640 + k * 2) ^ (unsigned int)((r & 7) << 4);
        *reinterpret_cast<uint2*>(reinterpret_cast<char*>(xs) + byte) = *reinterpret_cast<const uint2*>(vv);
    }
    // stage wc (rows kid*32 + p*8 + b), swizzled stride 256B
    for (int i = t; i < 64 * 32; i += 256) {
        int r = i >> 5, ch = i & 31;
        int kid = r >> 5, pr = r & 31, p = pr >> 3, b = pr & 7;
        int e = ch * 4;
        ushort_t vv[4] = {0, 0, 0, 0};
        if (e < EDIM && (nb + p) < n) {
            float4 xv = *reinterpret_cast<const float4*>(
                &edge_inputs[((size_t)b * NN + 2 * (start + nb + p) + 1 + kid) * EDIM + e]);
            vv[0] = f2b(xv.x); vv[1] = f2b(xv.y); vv[2] = f2b(xv.z); vv[3] = f2b(xv.w);
        }
        unsigned int byte = (unsigned int)(r * 256 + e * 2) ^ (unsigned int)((r & 7) << 4);
        *reinterpret_cast<uint2*>(reinterpret_cast<char*>(wc) + byte) = *reinterpret_cast<const uint2*>(vv);
    }
    __syncthreads();

    const bf16x8* fWfx = reinterpret_cast<const bf16x8*>(pWfx);
    const bf16x8* fWfh = reinterpret_cast<const bf16x8*>(pWfh);
    const bf16x8* fWe  = reinterpret_cast<const bf16x8*>(pWe);

    // per-lane A-frag offsets for f GEMM
    unsigned int cbase[4];
#pragma unroll
    for (int mt = 0; mt < 4; ++mt) {
        int kid = mt >> 1, mh = mt & 1;
        int p = 2 * mh + (cl >> 3);
        int b = cl & 7;
        cbase[mt] = ((nb + p) < n)
            ? (unsigned int)((nb + p) * 8192 + (kr * 16 + 8 * kid + b) * 8)
            : 0u;
    }

#pragma unroll 1
    for (int pp = 0; pp < 2; ++pp) {
        const int ntb = w * 8 + pp * 4;

        // ---- xf GEMM (K=320, rows mh*16+cl); result packed to 16 regs
        unsigned int xfp[4][2][2];
        {
            f32x4 xfa[4][2];
#pragma unroll
            for (int q = 0; q < 4; ++q)
#pragma unroll
                for (int mh = 0; mh < 2; ++mh)
#pragma unroll
                    for (int r = 0; r < 4; ++r) xfa[q][mh][r] = 0.f;
#pragma unroll 2
            for (int kt = 0; kt < 10; ++kt) {
                bf16x8 a0 = xs_frag(xs, cl, kt, kr);
                bf16x8 a1 = xs_frag(xs, 16 + cl, kt, kr);
#pragma unroll
                for (int q = 0; q < 4; ++q) {
                    bf16x8 bf_ = fWfx[(size_t)((ntb + q) * 10 + kt) * 64 + lane];
                    xfa[q][0] = __builtin_amdgcn_mfma_f32_16x16x32_bf16(a0, bf_, xfa[q][0], 0, 0, 0);
                    xfa[q][1] = __builtin_amdgcn_mfma_f32_16x16x32_bf16(a1, bf_, xfa[q][1], 0, 0, 0);
                }
            }
#pragma unroll
            for (int q = 0; q < 4; ++q) {
                float bv = bfx[(ntb + q) * 16 + cl];
#pragma unroll
                for (int mh = 0; mh < 2; ++mh) {
                    xfp[q][mh][0] = ((unsigned int)f2b(xfa[q][mh][1] + bv) << 16) | f2b(xfa[q][mh][0] + bv);
                    xfp[q][mh][1] = ((unsigned int)f2b(xfa[q][mh][3] + bv) << 16) | f2b(xfa[q][mh][2] + bv);
                }
            }
        }

        // ---- ex GEMM (K=128)
        {
            f32x4 eacc[4][4];
#pragma unroll
            for (int q = 0; q < 4; ++q)
#pragma unroll
                for (int mt = 0; mt < 4; ++mt)
#pragma unroll
                    for (int r = 0; r < 4; ++r) eacc[q][mt][r] = 0.f;
#pragma unroll
            for (int kt = 0; kt < 4; ++kt) {
                bf16x8 av[4];
#pragma unroll
                for (int mt = 0; mt < 4; ++mt)
                    av[mt] = sw_frag(wc, mt * 16 + cl, kt * 64 + kr * 16, 256);
#pragma unroll
                for (int q = 0; q < 4; ++q) {
                    bf16x8 bf_ = fWe[(size_t)((ntb + q) * 4 + kt) * 64 + lane];
#pragma unroll
                    for (int mt = 0; mt < 4; ++mt)
                        eacc[q][mt] = __builtin_amdgcn_mfma_f32_16x16x32_bf16(av[mt], bf_, eacc[q][mt], 0, 0, 0);
                }
            }
            // two rounds: write 128-col half-plane, apply
#pragma unroll 1
            for (int rd = 0; rd < 2; ++rd) {
                if ((w >> 1) == rd) {
#pragma unroll
                    for (int q = 0; q < 4; ++q) {
                        float bev = be[(ntb + q) * 16 + cl];
#pragma unroll
                        for (int mt = 0; mt < 4; ++mt)
#pragma unroll
                            for (int r = 0; r < 4; ++r)
                                sw_store2(epi, mt * 16 + kr * 4 + r, ((w & 1) * 4 + q) * 16 + cl,
                                          f2b(sigmoidf_(eacc[q][mt][r] + bev)), 256);
                    }
                }
                __syncthreads();
#pragma unroll
                for (int it = 0; it < 2; ++it) {
                    int task = it * 256 + t;
                    int pb = task >> 4, cbl = task & 15;
                    int cb_g = rd * 16 + cbl;
                    int p = pb >> 3, b = pb & 7;
                    if (nb + p < n) {
                        int nt = ((cb_g >> 3) << 3) + pp * 4 + ((cb_g >> 1) & 3);
                        int hh = cb_g & 1;
                        int colc = (nt >> 1) * 512 + (((nt & 1) << 1) + hh) * 128;
                        int lc0 = (cb_g & 15) * 8;
                        bf16x8 e0 = sw_frag(epi, pb, lc0 * 2, 256);
                        bf16x8 e1 = sw_frag(epi, 32 + pb, lc0 * 2, 256);
                        const ushort_t* hb = hX + (unsigned int)((nb + p) * 8192 + colc + b * 8);
                        bf16x8 h0 = *reinterpret_cast<const bf16x8*>(hb);
                        bf16x8 h1 = *reinterpret_cast<const bf16x8*>(hb + 64);
                        ushort_t res[8];
#pragma unroll
                        for (int i = 0; i < 8; ++i)
                            res[i] = f2b(b2f((ushort_t)e0[i]) * b2f((ushort_t)h0[i])
                                       + b2f((ushort_t)e1[i]) * b2f((ushort_t)h1[i]));
                        *reinterpret_cast<uint4*>(hY + (unsigned int)(((nb + p) >> 1) * 8192 + colc
                                + ((((nb + p) & 1) << 3) + b) * 8)) = *reinterpret_cast<const uint4*>(res);
                    }
                }
                __syncthreads();
            }
        }

        // ---- f GEMM (K=512, A preloaded double-buffer)
        {
            f32x4 facc[4][4];
#pragma unroll
            for (int q = 0; q < 4; ++q)
#pragma unroll
                for (int mt = 0; mt < 4; ++mt)
#pragma unroll
                    for (int r = 0; r < 4; ++r) facc[q][mt][r] = 0.f;

            bf16x8 avc[4], avn[4];
#pragma unroll
            for (int mt = 0; mt < 4; ++mt)
                avc[mt] = *reinterpret_cast<const bf16x8*>(hX + cbase[mt]);
#pragma unroll 2
            for (int kt = 0; kt < 16; ++kt) {
                if (kt < 15) {
#pragma unroll
                    for (int mt = 0; mt < 4; ++mt)
                        avn[mt] = *reinterpret_cast<const bf16x8*>(hX + cbase[mt] + (kt + 1) * 512u);
                }
#pragma unroll
                for (int q = 0; q < 4; ++q) {
                    bf16x8 bf_ = fWfh[(size_t)((ntb + q) * 16 + kt) * 64 + lane];
#pragma unroll
                    for (int mt = 0; mt < 4; ++mt)
                        facc[q][mt] = __builtin_amdgcn_mfma_f32_16x16x32_bf16(avc[mt], bf_, facc[q][mt], 0, 0, 0);
                }
#pragma unroll
                for (int mt = 0; mt < 4; ++mt) avc[mt] = avn[mt];
            }

#pragma unroll 1
            for (int rd = 0; rd < 2; ++rd) {
                if ((w >> 1) == rd) {
#pragma unroll
                    for (int q = 0; q < 4; ++q) {
                        float bfhv = bfh[(ntb + q) * 16 + cl];
#pragma unroll
                        for (int mt = 0; mt < 4; ++mt)
#pragma unroll
                            for (int r = 0; r < 4; ++r) {
                                float xfv = b2f((ushort_t)((xfp[q][mt & 1][r >> 1] >> ((r & 1) * 16)) & 0xffffu));
                                sw_store2(epi, mt * 16 + kr * 4 + r, ((w & 1) * 4 + q) * 16 + cl,
                                          f2b(sigmoidf_(facc[q][mt][r] + bfhv + xfv)), 256);
                            }
                    }
                }
                __syncthreads();
#pragma unroll
                for (int it = 0; it < 2; ++it) {
                    int task = it * 256 + t;
                    int pb = task >> 4, cbl = task & 15;
                    int cb_g = rd * 16 + cbl;
                    int p = pb >> 3, b = pb & 7;
                    if (nb + p < n) {
                        int nt = ((cb_g >> 3) << 3) + pp * 4 + ((cb_g >> 1) & 3);
                        int hh = cb_g & 1;
                        int colc = (nt >> 1) * 512 + (((nt & 1) << 1) + hh) * 128;
                        int lc0 = (cb_g & 15) * 8;
                        bf16x8 f0 = sw_frag(epi, pb, lc0 * 2, 256);
                        bf16x8 f1 = sw_frag(epi, 32 + pb, lc0 * 2, 256);
                        const ushort_t* cb_ = cX + (unsigned int)((nb + p) * 8192 + colc + b * 8);
                        bf16x8 c0 = *reinterpret_cast<const bf16x8*>(cb_);
                        bf16x8 c1 = *reinterpret_cast<const bf16x8*>(cb_ + 64);
                        ushort_t res[8];
#pragma unroll
                        for (int i = 0; i < 8; ++i)
                            res[i] = f2b(b2f((ushort_t)f0[i]) * b2f((ushort_t)c0[i])
                                       + b2f((ushort_t)f1[i]) * b2f((ushort_t)c1[i]));
                        *reinterpret_cast<uint4*>(cY + (unsigned int)(((nb + p) >> 1) * 8192 + colc
                                + ((((nb + p) & 1) << 3) + b) * 8)) = *reinterpret_cast<const uint4*>(res);
                    }
                }
                __syncthreads();
            }
        }
    }
}

// ---------------- iou v5 (also leaf): 8 parents/block; 48KB LDS, 3 blocks/CU, A-preload,
// single 8KB plane used in two passes (P1 then P2).
template <bool LEAF>
__global__ __launch_bounds__(256, 3) void iou_kernel(
    const float* __restrict__ inputs,
    const ushort_t* __restrict__ pWioux, const float* __restrict__ bioux,
    const ushort_t* __restrict__ pWiouh, const float* __restrict__ biouh,
    const ushort_t* __restrict__ hYsum, const ushort_t* __restrict__ cYfc,
    ushort_t* __restrict__ hOut, ushort_t* __restrict__ cOut,
    int start, int n)
{
    const int nb = blockIdx.x * 8;
    const int t = threadIdx.x;
    const int w = t >> 6, lane = t & 63;
    const int kr = lane >> 4, cl = lane & 15;

    __shared__ ushort_t xs[64 * 320];    // 40 KB swizzled
    __shared__ ushort_t plane[64 * 64];  // 8 KB swizzled (stride 128B)

    for (int i = t; i < 64 * 80; i += 256) {
        int r = i / 80, ch = i - r * 80;
        int p = r >> 3, b = r & 7, k = ch * 4;
        ushort_t vv[4] = {0, 0, 0, 0};
        if (k < INDIM && (nb + p) < n) {
            float4 xv = *reinterpret_cast<const float4*>(
                &inputs[((size_t)b * NN + start + nb + p) * INDIM + k]);
            vv[0] = f2b(xv.x); vv[1] = f2b(xv.y); vv[2] = f2b(xv.z); vv[3] = f2b(xv.w);
        }
        unsigned int byte = (unsigned int)(r * 640 + k * 2) ^ (unsigned int)((r & 7) << 4);
        *reinterpret_cast<uint2*>(reinterpret_cast<char*>(xs) + byte) = *reinterpret_cast<const uint2*>(vv);
    }
    __syncthreads();

    const bf16x8* fWx = reinterpret_cast<const bf16x8*>(pWioux);
    const bf16x8* fWh = reinterpret_cast<const bf16x8*>(pWiouh);

    unsigned int hbase[4];
#pragma unroll
    for (int mt = 0; mt < 4; ++mt)
        hbase[mt] = (unsigned int)(((nb >> 1) + mt) * 8192 + lane * 8);

#pragma unroll 1
    for (int j = 0; j < 8; ++j) {
        const int cnt = j * 4 + w;
        f32x4 acc[4][3];
#pragma unroll
        for (int mt = 0; mt < 4; ++mt)
#pragma unroll
            for (int q = 0; q < 3; ++q)
#pragma unroll
                for (int r = 0; r < 4; ++r) acc[mt][q][r] = 0.f;

#pragma unroll 2
        for (int kt = 0; kt < 10; ++kt) {
            bf16x8 av[4];
#pragma unroll
            for (int mt = 0; mt < 4; ++mt)
                av[mt] = xs_frag(xs, mt * 16 + cl, kt, kr);
#pragma unroll
            for (int q = 0; q < 3; ++q) {
                bf16x8 bf_ = fWx[(size_t)((q * 32 + cnt) * 10 + kt) * 64 + lane];
#pragma unroll
                for (int mt = 0; mt < 4; ++mt)
                    acc[mt][q] = __builtin_amdgcn_mfma_f32_16x16x32_bf16(av[mt], bf_, acc[mt][q], 0, 0, 0);
            }
        }
        if (!LEAF) {
            bf16x8 avc[4], avn[4];
#pragma unroll
            for (int mt = 0; mt < 4; ++mt)
                avc[mt] = *reinterpret_cast<const bf16x8*>(hYsum + hbase[mt]);
#pragma unroll 2
            for (int kt = 0; kt < 16; ++kt) {
                if (kt < 15) {
#pragma unroll
                    for (int mt = 0; mt < 4; ++mt)
                        avn[mt] = *reinterpret_cast<const bf16x8*>(hYsum + hbase[mt] + (kt + 1) * 512u);
                }
#pragma unroll
                for (int q = 0; q < 3; ++q) {
                    bf16x8 bf_ = fWh[(size_t)((q * 32 + cnt) * 16 + kt) * 64 + lane];
#pragma unroll
                    for (int mt = 0; mt < 4; ++mt)
                        acc[mt][q] = __builtin_amdgcn_mfma_f32_16x16x32_bf16(avc[mt], bf_, acc[mt][q], 0, 0, 0);
                }
#pragma unroll
                for (int mt = 0; mt < 4; ++mt) avc[mt] = avn[mt];
            }
        }

        const int col = cnt * 16 + cl;
        const float bi = bioux[col]        + biouh[col];
        const float bo = bioux[col + 512]  + biouh[col + 512];
        const float bu = bioux[col + 1024] + biouh[col + 1024];

        // ---- pass 1: P1 = sig(i)*tanh(u)
#pragma unroll
        for (int mt = 0; mt < 4; ++mt)
#pragma unroll
            for (int r = 0; r < 4; ++r)
                sw_store2(plane, mt * 16 + kr * 4 + r, w * 16 + cl,
                          f2b(sigmoidf_(acc[mt][0][r] + bi) * tanhf(acc[mt][2][r] + bu)), 128);
        __syncthreads();

        float tanhc[2][8];
        unsigned int oo[2];
        bool val[2];
#pragma unroll
        for (int it = 0; it < 2; ++it) {
            int task = it * 256 + t;
            int rowid = task >> 3, ch = task & 7;
            int p = rowid >> 3, b = rowid & 7;
            val[it] = (nb + p) < n;
            if (val[it]) {
                int lc0 = ch * 8;
                int c2 = j * 4 + (ch >> 1);
                int hh = ch & 1;
                int colc = (c2 >> 1) * 512 + (((c2 & 1) << 1) + hh) * 128;
                unsigned int o = (unsigned int)(((nb + p) >> 1) * 8192 + colc
                                                + ((((nb + p) & 1) << 3) + b) * 8);
                oo[it] = o;
                bf16x8 v1 = sw_frag(plane, rowid, lc0 * 2, 128);
                bf16x8 vf = zero8();
                if (!LEAF) vf = *reinterpret_cast<const bf16x8*>(cYfc + o);
                ushort_t rc[8];
#pragma unroll
                for (int i = 0; i < 8; ++i) {
                    float cv = b2f((ushort_t)v1[i]) + b2f((ushort_t)vf[i]);
                    rc[i] = f2b(cv);
                    tanhc[it][i] = tanhf(cv);
                }
                *reinterpret_cast<uint4*>(cOut + o) = *reinterpret_cast<const uint4*>(rc);
            }
        }
        __syncthreads();

        // ---- pass 2: P2 = sig(o)
#pragma unroll
        for (int mt = 0; mt < 4; ++mt)
#pragma unroll
            for (int r = 0; r < 4; ++r)
                sw_store2(plane, mt * 16 + kr * 4 + r, w * 16 + cl,
                          f2b(sigmoidf_(acc[mt][1][r] + bo)), 128);
        __syncthreads();

#pragma unroll
        for (int it = 0; it < 2; ++it) {
            if (val[it]) {
                int task = it * 256 + t;
                int rowid = task >> 3, ch = task & 7;
                bf16x8 v2 = sw_frag(plane, rowid, (ch * 8) * 2, 128);
                ushort_t rh[8];
#pragma unroll
                for (int i = 0; i < 8; ++i)
                    rh[i] = f2b(b2f((ushort_t)v2[i]) * tanhc[it][i]);
                *reinterpret_cast<uint4*>(hOut + oo[it]) = *reinterpret_cast<const uint4*>(rh);
            }
        }
        __syncthreads();
    }
}

// ---------------- output: concat(c_root, h_root) per batch, FP32 (packed-layout read)
__global__ __launch_bounds__(256) void out_kernel(
    const ushort_t* __restrict__ hroot, const ushort_t* __restrict__ croot,
    float* __restrict__ out)
{
    int t = blockIdx.x * 256 + threadIdx.x;
    if (t >= B * 2 * HDIM) return;
    int b = t / (2 * HDIM);
    int j = t - b * 2 * HDIM;
    int col = (j < HDIM) ? j : j - HDIM;
    unsigned int o = pidx(b, col);
    out[t] = (j < HDIM) ? b2f(croot[o]) : b2f(hroot[o]);
}

__global__ void diag_kernel(float* out, float v) { out[0] = v; }

extern "C" void kernel_launch(void* const* d_in, const int* in_sizes, int n_in,
                              void* d_out, int out_size, void* d_ws, size_t ws_size,
                              hipStream_t stream)
{
    const float* inputs      = (const float*)d_in[0];
    const float* edge_inputs = (const float*)d_in[1];
    const float* Wioux       = (const float*)d_in[2];
    const float* bioux       = (const float*)d_in[3];
    const float* Wiouh       = (const float*)d_in[4];
    const float* biouh       = (const float*)d_in[5];
    const float* Wfx         = (const float*)d_in[6];
    const float* bfx         = (const float*)d_in[7];
    const float* Wfh         = (const float*)d_in[8];
    const float* bfh         = (const float*)d_in[9];
    const float* We          = (const float*)d_in[10];
    const float* be          = (const float*)d_in[11];
    float* out = (float*)d_out;

    const size_t szWioux = (size_t)96 * 10 * 64 * 8;
    const size_t szWfx   = (size_t)32 * 10 * 64 * 8;
    const size_t szWe    = (size_t)32 * 4  * 64 * 8;
    const size_t szWfh   = (size_t)32 * 16 * 64 * 8;
    const size_t szWiouh = (size_t)96 * 16 * 64 * 8;

    const size_t eX = (size_t)B * 8192 * HDIM;
    const size_t eY = (size_t)B * 4096 * HDIM;

    const size_t need = (szWioux + szWfx + szWe + szWfh + szWiouh
                         + 2 * eX + 2 * eY) * sizeof(ushort_t);  // ~204.9 MB
    if (ws_size < need) {
        diag_kernel<<<1, 1, 0, stream>>>(out, 2.0e8f);
        return;
    }

    ushort_t* p = (ushort_t*)d_ws;
    ushort_t* pWioux = p;            p += szWioux;
    ushort_t* pWfx   = p;            p += szWfx;
    ushort_t* pWe    = p;            p += szWe;
    ushort_t* pWfh   = p;            p += szWfh;
    ushort_t* pWiouh = p;            p += szWiouh;
    ushort_t* hX = p;                p += eX;
    ushort_t* cX = p;                p += eX;
    ushort_t* hY = p;                p += eY;
    ushort_t* cY = p;                p += eY;

    pack_kernel<<<(96 * 10 * 64 + 255) / 256, 256, 0, stream>>>(Wioux, pWioux, INDIM, 10, 96 * 10 * 64);
    pack_kernel<<<(32 * 10 * 64 + 255) / 256, 256, 0, stream>>>(Wfx,   pWfx,   INDIM, 10, 32 * 10 * 64);
    pack_kernel<<<(32 * 4  * 64 + 255) / 256, 256, 0, stream>>>(We,    pWe,    EDIM,  4,  32 * 4  * 64);
    pack_kernel<<<(32 * 16 * 64 + 255) / 256, 256, 0, stream>>>(Wfh,   pWfh,   HDIM,  16, 32 * 16 * 64);
    pack_kernel<<<(96 * 16 * 64 + 255) / 256, 256, 0, stream>>>(Wiouh, pWiouh, HDIM,  16, 96 * 16 * 64);

    // leaf level: start=8191, n=8192
    iou_kernel<true><<<1024, 256, 0, stream>>>(inputs, pWioux, bioux, pWiouh, biouh,
                                               hY, cY, hX, cX, 8191, 8192);

    for (int lvl = 12; lvl >= 0; --lvl) {
        int start = (1 << lvl) - 1;
        int n = 1 << lvl;
        children_kernel<<<(n + 3) / 4, 256, 0, stream>>>(
            inputs, edge_inputs, pWfx, bfx, pWfh, bfh, pWe, be,
            hX, cX, hY, cY, start, n);
        iou_kernel<false><<<(n + 7) / 8, 256, 0, stream>>>(
            inputs, pWioux, bioux, pWiouh, biouh,
            hY, cY, hX, cX, start, n);
    }

    out_kernel<<<(B * 2 * HDIM + 255) / 256, 256, 0, stream>>>(hX, cX, out);
}

// Round 11
// 3988.061 us; speedup vs baseline: 1.2445x; 1.2445x over previous
//
#include <hip/hip_runtime.h>
#include <hip/hip_bf16.h>
#include <stdint.h>

#define B 8
#define NN 16383
#define INDIM 300
#define HDIM 512
#define EDIM 100

typedef short bf16x8 __attribute__((ext_vector_type(8)));
typedef float f32x4 __attribute__((ext_vector_type(4)));
typedef unsigned short ushort_t;

__device__ __forceinline__ float sigmoidf_(float v) { return 1.0f / (1.0f + __expf(-v)); }

__device__ __forceinline__ ushort_t f2b(float f) {
    union { float f; unsigned int u; } x; x.f = f;
    unsigned int u = x.u;
    return (ushort_t)((u + 0x7FFFu + ((u >> 16) & 1u)) >> 16);
}
__device__ __forceinline__ float b2f(ushort_t s) {
    union { float f; unsigned int u; } x; x.u = ((unsigned int)s) << 16; return x.f;
}
__device__ __forceinline__ bf16x8 zero8() {
    bf16x8 v;
#pragma unroll
    for (int i = 0; i < 8; ++i) v[i] = 0;
    return v;
}

// packed h/c layout (K=512): elem (R, col) ->
//   (R>>4)*8192 + (col>>5)*512 + ((col>>3)&3)*128 + (R&15)*8 + (col&7)
__device__ __forceinline__ unsigned int pidx(int R, int col) {
    return (unsigned int)((R >> 4) * 8192 + (col >> 5) * 512 + ((col >> 3) & 3) * 128
                          + (R & 15) * 8 + (col & 7));
}

// swizzled LDS xs (stride 320 ushorts = 640B), frag read 16B
__device__ __forceinline__ bf16x8 xs_frag(const ushort_t* xs, int row, int kt, int kr) {
    unsigned int byte = (unsigned int)(row * 640 + kt * 64 + kr * 16) ^ (unsigned int)((row & 7) << 4);
    return *reinterpret_cast<const bf16x8*>(reinterpret_cast<const char*>(xs) + byte);
}
// swizzled LDS, generic stride (bytes), 16B frag read / 2B store
__device__ __forceinline__ bf16x8 sw_frag(const ushort_t* buf, int row, int lc_bytes, int stride) {
    unsigned int byte = (unsigned int)(row * stride + lc_bytes) ^ (unsigned int)((row & 7) << 4);
    return *reinterpret_cast<const bf16x8*>(reinterpret_cast<const char*>(buf) + byte);
}
__device__ __forceinline__ void sw_store2(ushort_t* buf, int row, int lc, ushort_t v, int stride) {
    unsigned int byte = (unsigned int)(row * stride + lc * 2) ^ (unsigned int)((row & 7) << 4);
    *reinterpret_cast<ushort_t*>(reinterpret_cast<char*>(buf) + byte) = v;
}

// ---------------- pack weights into MFMA B-fragment order.
__global__ __launch_bounds__(256) void pack_kernel(
    const float* __restrict__ W, ushort_t* __restrict__ out,
    int Kdim, int Kt, int total)
{
    int idx = blockIdx.x * 256 + threadIdx.x;
    if (idx >= total) return;
    int lane = idx & 63;
    int kt = (idx >> 6) % Kt;
    int nt = idx / (Kt << 6);
    int n = nt * 16 + (lane & 15);
    int kb = kt * 32 + (lane >> 4) * 8;
    ushort_t v[8];
#pragma unroll
    for (int i = 0; i < 8; ++i) {
        int k = kb + i;
        v[i] = (k < Kdim) ? f2b(W[(size_t)n * Kdim + k]) : (ushort_t)0;
    }
    *reinterpret_cast<uint4*>(out + (size_t)idx * 8) = *reinterpret_cast<const uint4*>(v);
}

// ---------------- children v6: 4 parents/block; 52KB LDS (3 blocks/CU by LDS), regs uncapped.
__global__ __launch_bounds__(256) void children_kernel(
    const float* __restrict__ inputs, const float* __restrict__ edge_inputs,
    const ushort_t* __restrict__ pWfx, const float* __restrict__ bfx,
    const ushort_t* __restrict__ pWfh, const float* __restrict__ bfh,
    const ushort_t* __restrict__ pWe,  const float* __restrict__ be,
    const ushort_t* __restrict__ hX, const ushort_t* __restrict__ cX,
    ushort_t* __restrict__ hY, ushort_t* __restrict__ cY,
    int start, int n)
{
    const int nb = blockIdx.x * 4;
    const int t = threadIdx.x;
    const int w = t >> 6, lane = t & 63;
    const int kr = lane >> 4, cl = lane & 15;

    __shared__ ushort_t xs[32 * 320];   // 20 KB swizzled (stride 640B)
    __shared__ ushort_t wc[64 * 128];   // 16 KB swizzled (stride 256B)
    __shared__ ushort_t epi[64 * 128];  // 16 KB swizzled (stride 256B), half-width plane

    // stage x (rows p*8+b, 4 parents)
    for (int i = t; i < 32 * 80; i += 256) {
        int r = i / 80, ch = i - r * 80;
        int p = r >> 3, b = r & 7, k = ch * 4;
        ushort_t vv[4] = {0, 0, 0, 0};
        if (k < INDIM && (nb + p) < n) {
            float4 xv = *reinterpret_cast<const float4*>(
                &inputs[((size_t)b * NN + start + nb + p) * INDIM + k]);
            vv[0] = f2b(xv.x); vv[1] = f2b(xv.y); vv[2] = f2b(xv.z); vv[3] = f2b(xv.w);
        }
        unsigned int byte = (unsigned int)(r * 640 + k * 2) ^ (unsigned int)((r & 7) << 4);
        *reinterpret_cast<uint2*>(reinterpret_cast<char*>(xs) + byte) = *reinterpret_cast<const uint2*>(vv);
    }
    // stage wc (rows kid*32 + p*8 + b), swizzled stride 256B
    for (int i = t; i < 64 * 32; i += 256) {
        int r = i >> 5, ch = i & 31;
        int kid = r >> 5, pr = r & 31, p = pr >> 3, b = pr & 7;
        int e = ch * 4;
        ushort_t vv[4] = {0, 0, 0, 0};
        if (e < EDIM && (nb + p) < n) {
            float4 xv = *reinterpret_cast<const float4*>(
                &edge_inputs[((size_t)b * NN + 2 * (start + nb + p) + 1 + kid) * EDIM + e]);
            vv[0] = f2b(xv.x); vv[1] = f2b(xv.y); vv[2] = f2b(xv.z); vv[3] = f2b(xv.w);
        }
        unsigned int byte = (unsigned int)(r * 256 + e * 2) ^ (unsigned int)((r & 7) << 4);
        *reinterpret_cast<uint2*>(reinterpret_cast<char*>(wc) + byte) = *reinterpret_cast<const uint2*>(vv);
    }
    __syncthreads();

    const bf16x8* fWfx = reinterpret_cast<const bf16x8*>(pWfx);
    const bf16x8* fWfh = reinterpret_cast<const bf16x8*>(pWfh);
    const bf16x8* fWe  = reinterpret_cast<const bf16x8*>(pWe);

    // per-lane A-frag offsets for f GEMM
    unsigned int cbase[4];
#pragma unroll
    for (int mt = 0; mt < 4; ++mt) {
        int kid = mt >> 1, mh = mt & 1;
        int p = 2 * mh + (cl >> 3);
        int b = cl & 7;
        cbase[mt] = ((nb + p) < n)
            ? (unsigned int)((nb + p) * 8192 + (kr * 16 + 8 * kid + b) * 8)
            : 0u;
    }

#pragma unroll 1
    for (int pp = 0; pp < 2; ++pp) {
        const int ntb = w * 8 + pp * 4;

        // ---- xf GEMM (K=320, rows mh*16+cl); result packed to 16 regs
        unsigned int xfp[4][2][2];
        {
            f32x4 xfa[4][2];
#pragma unroll
            for (int q = 0; q < 4; ++q)
#pragma unroll
                for (int mh = 0; mh < 2; ++mh)
#pragma unroll
                    for (int r = 0; r < 4; ++r) xfa[q][mh][r] = 0.f;
#pragma unroll 2
            for (int kt = 0; kt < 10; ++kt) {
                bf16x8 a0 = xs_frag(xs, cl, kt, kr);
                bf16x8 a1 = xs_frag(xs, 16 + cl, kt, kr);
#pragma unroll
                for (int q = 0; q < 4; ++q) {
                    bf16x8 bf_ = fWfx[(size_t)((ntb + q) * 10 + kt) * 64 + lane];
                    xfa[q][0] = __builtin_amdgcn_mfma_f32_16x16x32_bf16(a0, bf_, xfa[q][0], 0, 0, 0);
                    xfa[q][1] = __builtin_amdgcn_mfma_f32_16x16x32_bf16(a1, bf_, xfa[q][1], 0, 0, 0);
                }
            }
#pragma unroll
            for (int q = 0; q < 4; ++q) {
                float bv = bfx[(ntb + q) * 16 + cl];
#pragma unroll
                for (int mh = 0; mh < 2; ++mh) {
                    xfp[q][mh][0] = ((unsigned int)f2b(xfa[q][mh][1] + bv) << 16) | f2b(xfa[q][mh][0] + bv);
                    xfp[q][mh][1] = ((unsigned int)f2b(xfa[q][mh][3] + bv) << 16) | f2b(xfa[q][mh][2] + bv);
                }
            }
        }

        // ---- ex GEMM (K=128)
        {
            f32x4 eacc[4][4];
#pragma unroll
            for (int q = 0; q < 4; ++q)
#pragma unroll
                for (int mt = 0; mt < 4; ++mt)
#pragma unroll
                    for (int r = 0; r < 4; ++r) eacc[q][mt][r] = 0.f;
#pragma unroll
            for (int kt = 0; kt < 4; ++kt) {
                bf16x8 av[4];
#pragma unroll
                for (int mt = 0; mt < 4; ++mt)
                    av[mt] = sw_frag(wc, mt * 16 + cl, kt * 64 + kr * 16, 256);
#pragma unroll
                for (int q = 0; q < 4; ++q) {
                    bf16x8 bf_ = fWe[(size_t)((ntb + q) * 4 + kt) * 64 + lane];
#pragma unroll
                    for (int mt = 0; mt < 4; ++mt)
                        eacc[q][mt] = __builtin_amdgcn_mfma_f32_16x16x32_bf16(av[mt], bf_, eacc[q][mt], 0, 0, 0);
                }
            }
            // two rounds: write 128-col half-plane, apply
#pragma unroll 1
            for (int rd = 0; rd < 2; ++rd) {
                if ((w >> 1) == rd) {
#pragma unroll
                    for (int q = 0; q < 4; ++q) {
                        float bev = be[(ntb + q) * 16 + cl];
#pragma unroll
                        for (int mt = 0; mt < 4; ++mt)
#pragma unroll
                            for (int r = 0; r < 4; ++r)
                                sw_store2(epi, mt * 16 + kr * 4 + r, ((w & 1) * 4 + q) * 16 + cl,
                                          f2b(sigmoidf_(eacc[q][mt][r] + bev)), 256);
                    }
                }
                __syncthreads();
#pragma unroll
                for (int it = 0; it < 2; ++it) {
                    int task = it * 256 + t;
                    int pb = task >> 4, cbl = task & 15;
                    int cb_g = rd * 16 + cbl;
                    int p = pb >> 3, b = pb & 7;
                    if (nb + p < n) {
                        int nt = ((cb_g >> 3) << 3) + pp * 4 + ((cb_g >> 1) & 3);
                        int hh = cb_g & 1;
                        int colc = (nt >> 1) * 512 + (((nt & 1) << 1) + hh) * 128;
                        int lc0 = (cb_g & 15) * 8;
                        bf16x8 e0 = sw_frag(epi, pb, lc0 * 2, 256);
                        bf16x8 e1 = sw_frag(epi, 32 + pb, lc0 * 2, 256);
                        const ushort_t* hb = hX + (unsigned int)((nb + p) * 8192 + colc + b * 8);
                        bf16x8 h0 = *reinterpret_cast<const bf16x8*>(hb);
                        bf16x8 h1 = *reinterpret_cast<const bf16x8*>(hb + 64);
                        ushort_t res[8];
#pragma unroll
                        for (int i = 0; i < 8; ++i)
                            res[i] = f2b(b2f((ushort_t)e0[i]) * b2f((ushort_t)h0[i])
                                       + b2f((ushort_t)e1[i]) * b2f((ushort_t)h1[i]));
                        *reinterpret_cast<uint4*>(hY + (unsigned int)(((nb + p) >> 1) * 8192 + colc
                                + ((((nb + p) & 1) << 3) + b) * 8)) = *reinterpret_cast<const uint4*>(res);
                    }
                }
                __syncthreads();
            }
        }

        // ---- f GEMM (K=512, A preloaded double-buffer)
        {
            f32x4 facc[4][4];
#pragma unroll
            for (int q = 0; q < 4; ++q)
#pragma unroll
                for (int mt = 0; mt < 4; ++mt)
#pragma unroll
                    for (int r = 0; r < 4; ++r) facc[q][mt][r] = 0.f;

            bf16x8 avc[4], avn[4];
#pragma unroll
            for (int mt = 0; mt < 4; ++mt)
                avc[mt] = *reinterpret_cast<const bf16x8*>(hX + cbase[mt]);
#pragma unroll 2
            for (int kt = 0; kt < 16; ++kt) {
                if (kt < 15) {
#pragma unroll
                    for (int mt = 0; mt < 4; ++mt)
                        avn[mt] = *reinterpret_cast<const bf16x8*>(hX + cbase[mt] + (kt + 1) * 512u);
                }
#pragma unroll
                for (int q = 0; q < 4; ++q) {
                    bf16x8 bf_ = fWfh[(size_t)((ntb + q) * 16 + kt) * 64 + lane];
#pragma unroll
                    for (int mt = 0; mt < 4; ++mt)
                        facc[q][mt] = __builtin_amdgcn_mfma_f32_16x16x32_bf16(avc[mt], bf_, facc[q][mt], 0, 0, 0);
                }
#pragma unroll
                for (int mt = 0; mt < 4; ++mt) avc[mt] = avn[mt];
            }

#pragma unroll 1
            for (int rd = 0; rd < 2; ++rd) {
                if ((w >> 1) == rd) {
#pragma unroll
                    for (int q = 0; q < 4; ++q) {
                        float bfhv = bfh[(ntb + q) * 16 + cl];
#pragma unroll
                        for (int mt = 0; mt < 4; ++mt)
#pragma unroll
                            for (int r = 0; r < 4; ++r) {
                                float xfv = b2f((ushort_t)((xfp[q][mt & 1][r >> 1] >> ((r & 1) * 16)) & 0xffffu));
                                sw_store2(epi, mt * 16 + kr * 4 + r, ((w & 1) * 4 + q) * 16 + cl,
                                          f2b(sigmoidf_(facc[q][mt][r] + bfhv + xfv)), 256);
                            }
                    }
                }
                __syncthreads();
#pragma unroll
                for (int it = 0; it < 2; ++it) {
                    int task = it * 256 + t;
                    int pb = task >> 4, cbl = task & 15;
                    int cb_g = rd * 16 + cbl;
                    int p = pb >> 3, b = pb & 7;
                    if (nb + p < n) {
                        int nt = ((cb_g >> 3) << 3) + pp * 4 + ((cb_g >> 1) & 3);
                        int hh = cb_g & 1;
                        int colc = (nt >> 1) * 512 + (((nt & 1) << 1) + hh) * 128;
                        int lc0 = (cb_g & 15) * 8;
                        bf16x8 f0 = sw_frag(epi, pb, lc0 * 2, 256);
                        bf16x8 f1 = sw_frag(epi, 32 + pb, lc0 * 2, 256);
                        const ushort_t* cb_ = cX + (unsigned int)((nb + p) * 8192 + colc + b * 8);
                        bf16x8 c0 = *reinterpret_cast<const bf16x8*>(cb_);
                        bf16x8 c1 = *reinterpret_cast<const bf16x8*>(cb_ + 64);
                        ushort_t res[8];
#pragma unroll
                        for (int i = 0; i < 8; ++i)
                            res[i] = f2b(b2f((ushort_t)f0[i]) * b2f((ushort_t)c0[i])
                                       + b2f((ushort_t)f1[i]) * b2f((ushort_t)c1[i]));
                        *reinterpret_cast<uint4*>(cY + (unsigned int)(((nb + p) >> 1) * 8192 + colc
                                + ((((nb + p) & 1) << 3) + b) * 8)) = *reinterpret_cast<const uint4*>(res);
                    }
                }
                __syncthreads();
            }
        }
    }
}

// ---------------- iou v6 (also leaf): 8 parents/block; 48KB LDS (3 blocks/CU), regs uncapped.
template <bool LEAF>
__global__ __launch_bounds__(256) void iou_kernel(
    const float* __restrict__ inputs,
    const ushort_t* __restrict__ pWioux, const float* __restrict__ bioux,
    const ushort_t* __restrict__ pWiouh, const float* __restrict__ biouh,
    const ushort_t* __restrict__ hYsum, const ushort_t* __restrict__ cYfc,
    ushort_t* __restrict__ hOut, ushort_t* __restrict__ cOut,
    int start, int n)
{
    const int nb = blockIdx.x * 8;
    const int t = threadIdx.x;
    const int w = t >> 6, lane = t & 63;
    const int kr = lane >> 4, cl = lane & 15;

    __shared__ ushort_t xs[64 * 320];    // 40 KB swizzled
    __shared__ ushort_t plane[64 * 64];  // 8 KB swizzled (stride 128B)

    for (int i = t; i < 64 * 80; i += 256) {
        int r = i / 80, ch = i - r * 80;
        int p = r >> 3, b = r & 7, k = ch * 4;
        ushort_t vv[4] = {0, 0, 0, 0};
        if (k < INDIM && (nb + p) < n) {
            float4 xv = *reinterpret_cast<const float4*>(
                &inputs[((size_t)b * NN + start + nb + p) * INDIM + k]);
            vv[0] = f2b(xv.x); vv[1] = f2b(xv.y); vv[2] = f2b(xv.z); vv[3] = f2b(xv.w);
        }
        unsigned int byte = (unsigned int)(r * 640 + k * 2) ^ (unsigned int)((r & 7) << 4);
        *reinterpret_cast<uint2*>(reinterpret_cast<char*>(xs) + byte) = *reinterpret_cast<const uint2*>(vv);
    }
    __syncthreads();

    const bf16x8* fWx = reinterpret_cast<const bf16x8*>(pWioux);
    const bf16x8* fWh = reinterpret_cast<const bf16x8*>(pWiouh);

    unsigned int hbase[4];
#pragma unroll
    for (int mt = 0; mt < 4; ++mt)
        hbase[mt] = (unsigned int)(((nb >> 1) + mt) * 8192 + lane * 8);

#pragma unroll 1
    for (int j = 0; j < 8; ++j) {
        const int cnt = j * 4 + w;
        f32x4 acc[4][3];
#pragma unroll
        for (int mt = 0; mt < 4; ++mt)
#pragma unroll
            for (int q = 0; q < 3; ++q)
#pragma unroll
                for (int r = 0; r < 4; ++r) acc[mt][q][r] = 0.f;

#pragma unroll 2
        for (int kt = 0; kt < 10; ++kt) {
            bf16x8 av[4];
#pragma unroll
            for (int mt = 0; mt < 4; ++mt)
                av[mt] = xs_frag(xs, mt * 16 + cl, kt, kr);
#pragma unroll
            for (int q = 0; q < 3; ++q) {
                bf16x8 bf_ = fWx[(size_t)((q * 32 + cnt) * 10 + kt) * 64 + lane];
#pragma unroll
                for (int mt = 0; mt < 4; ++mt)
                    acc[mt][q] = __builtin_amdgcn_mfma_f32_16x16x32_bf16(av[mt], bf_, acc[mt][q], 0, 0, 0);
            }
        }
        if (!LEAF) {
            bf16x8 avc[4], avn[4];
#pragma unroll
            for (int mt = 0; mt < 4; ++mt)
                avc[mt] = *reinterpret_cast<const bf16x8*>(hYsum + hbase[mt]);
#pragma unroll 2
            for (int kt = 0; kt < 16; ++kt) {
                if (kt < 15) {
#pragma unroll
                    for (int mt = 0; mt < 4; ++mt)
                        avn[mt] = *reinterpret_cast<const bf16x8*>(hYsum + hbase[mt] + (kt + 1) * 512u);
                }
#pragma unroll
                for (int q = 0; q < 3; ++q) {
                    bf16x8 bf_ = fWh[(size_t)((q * 32 + cnt) * 16 + kt) * 64 + lane];
#pragma unroll
                    for (int mt = 0; mt < 4; ++mt)
                        acc[mt][q] = __builtin_amdgcn_mfma_f32_16x16x32_bf16(avc[mt], bf_, acc[mt][q], 0, 0, 0);
                }
#pragma unroll
                for (int mt = 0; mt < 4; ++mt) avc[mt] = avn[mt];
            }
        }

        const int col = cnt * 16 + cl;
        const float bi = bioux[col]        + biouh[col];
        const float bo = bioux[col + 512]  + biouh[col + 512];
        const float bu = bioux[col + 1024] + biouh[col + 1024];

        // ---- pass 1: P1 = sig(i)*tanh(u)
#pragma unroll
        for (int mt = 0; mt < 4; ++mt)
#pragma unroll
            for (int r = 0; r < 4; ++r)
                sw_store2(plane, mt * 16 + kr * 4 + r, w * 16 + cl,
                          f2b(sigmoidf_(acc[mt][0][r] + bi) * tanhf(acc[mt][2][r] + bu)), 128);
        __syncthreads();

        float tanhc[2][8];
        unsigned int oo[2];
        bool val[2];
#pragma unroll
        for (int it = 0; it < 2; ++it) {
            int task = it * 256 + t;
            int rowid = task >> 3, ch = task & 7;
            int p = rowid >> 3, b = rowid & 7;
            val[it] = (nb + p) < n;
            if (val[it]) {
                int lc0 = ch * 8;
                int c2 = j * 4 + (ch >> 1);
                int hh = ch & 1;
                int colc = (c2 >> 1) * 512 + (((c2 & 1) << 1) + hh) * 128;
                unsigned int o = (unsigned int)(((nb + p) >> 1) * 8192 + colc
                                                + ((((nb + p) & 1) << 3) + b) * 8);
                oo[it] = o;
                bf16x8 v1 = sw_frag(plane, rowid, lc0 * 2, 128);
                bf16x8 vf = zero8();
                if (!LEAF) vf = *reinterpret_cast<const bf16x8*>(cYfc + o);
                ushort_t rc[8];
#pragma unroll
                for (int i = 0; i < 8; ++i) {
                    float cv = b2f((ushort_t)v1[i]) + b2f((ushort_t)vf[i]);
                    rc[i] = f2b(cv);
                    tanhc[it][i] = tanhf(cv);
                }
                *reinterpret_cast<uint4*>(cOut + o) = *reinterpret_cast<const uint4*>(rc);
            }
        }
        __syncthreads();

        // ---- pass 2: P2 = sig(o)
#pragma unroll
        for (int mt = 0; mt < 4; ++mt)
#pragma unroll
            for (int r = 0; r < 4; ++r)
                sw_store2(plane, mt * 16 + kr * 4 + r, w * 16 + cl,
                          f2b(sigmoidf_(acc[mt][1][r] + bo)), 128);
        __syncthreads();

#pragma unroll
        for (int it = 0; it < 2; ++it) {
            if (val[it]) {
                int task = it * 256 + t;
                int rowid = task >> 3, ch = task & 7;
                bf16x8 v2 = sw_frag(plane, rowid, (ch * 8) * 2, 128);
                ushort_t rh[8];
#pragma unroll
                for (int i = 0; i < 8; ++i)
                    rh[i] = f2b(b2f((ushort_t)v2[i]) * tanhc[it][i]);
                *reinterpret_cast<uint4*>(hOut + oo[it]) = *reinterpret_cast<const uint4*>(rh);
            }
        }
        __syncthreads();
    }
}

// ---------------- output: concat(c_root, h_root) per batch, FP32 (packed-layout read)
__global__ __launch_bounds__(256) void out_kernel(
    const ushort_t* __restrict__ hroot, const ushort_t* __restrict__ croot,
    float* __restrict__ out)
{
    int t = blockIdx.x * 256 + threadIdx.x;
    if (t >= B * 2 * HDIM) return;
    int b = t / (2 * HDIM);
    int j = t - b * 2 * HDIM;
    int col = (j < HDIM) ? j : j - HDIM;
    unsigned int o = pidx(b, col);
    out[t] = (j < HDIM) ? b2f(croot[o]) : b2f(hroot[o]);
}

__global__ void diag_kernel(float* out, float v) { out[0] = v; }

extern "C" void kernel_launch(void* const* d_in, const int* in_sizes, int n_in,
                              void* d_out, int out_size, void* d_ws, size_t ws_size,
                              hipStream_t stream)
{
    const float* inputs      = (const float*)d_in[0];
    const float* edge_inputs = (const float*)d_in[1];
    const float* Wioux       = (const float*)d_in[2];
    const float* bioux       = (const float*)d_in[3];
    const float* Wiouh       = (const float*)d_in[4];
    const float* biouh       = (const float*)d_in[5];
    const float* Wfx         = (const float*)d_in[6];
    const float* bfx         = (const float*)d_in[7];
    const float* Wfh         = (const float*)d_in[8];
    const float* bfh         = (const float*)d_in[9];
    const float* We          = (const float*)d_in[10];
    const float* be          = (const float*)d_in[11];
    float* out = (float*)d_out;

    const size_t szWioux = (size_t)96 * 10 * 64 * 8;
    const size_t szWfx   = (size_t)32 * 10 * 64 * 8;
    const size_t szWe    = (size_t)32 * 4  * 64 * 8;
    const size_t szWfh   = (size_t)32 * 16 * 64 * 8;
    const size_t szWiouh = (size_t)96 * 16 * 64 * 8;

    const size_t eX = (size_t)B * 8192 * HDIM;
    const size_t eY = (size_t)B * 4096 * HDIM;

    const size_t need = (szWioux + szWfx + szWe + szWfh + szWiouh
                         + 2 * eX + 2 * eY) * sizeof(ushort_t);  // ~204.9 MB
    if (ws_size < need) {
        diag_kernel<<<1, 1, 0, stream>>>(out, 2.0e8f);
        return;
    }

    ushort_t* p = (ushort_t*)d_ws;
    ushort_t* pWioux = p;            p += szWioux;
    ushort_t* pWfx   = p;            p += szWfx;
    ushort_t* pWe    = p;            p += szWe;
    ushort_t* pWfh   = p;            p += szWfh;
    ushort_t* pWiouh = p;            p += szWiouh;
    ushort_t* hX = p;                p += eX;
    ushort_t* cX = p;                p += eX;
    ushort_t* hY = p;                p += eY;
    ushort_t* cY = p;                p += eY;

    pack_kernel<<<(96 * 10 * 64 + 255) / 256, 256, 0, stream>>>(Wioux, pWioux, INDIM, 10, 96 * 10 * 64);
    pack_kernel<<<(32 * 10 * 64 + 255) / 256, 256, 0, stream>>>(Wfx,   pWfx,   INDIM, 10, 32 * 10 * 64);
    pack_kernel<<<(32 * 4  * 64 + 255) / 256, 256, 0, stream>>>(We,    pWe,    EDIM,  4,  32 * 4  * 64);
    pack_kernel<<<(32 * 16 * 64 + 255) / 256, 256, 0, stream>>>(Wfh,   pWfh,   HDIM,  16, 32 * 16 * 64);
    pack_kernel<<<(96 * 16 * 64 + 255) / 256, 256, 0, stream>>>(Wiouh, pWiouh, HDIM,  16, 96 * 16 * 64);

    // leaf level: start=8191, n=8192
    iou_kernel<true><<<1024, 256, 0, stream>>>(inputs, pWioux, bioux, pWiouh, biouh,
                                               hY, cY, hX, cX, 8191, 8192);

    for (int lvl = 12; lvl >= 0; --lvl) {
        int start = (1 << lvl) - 1;
        int n = 1 << lvl;
        children_kernel<<<(n + 3) / 4, 256, 0, stream>>>(
            inputs, edge_inputs, pWfx, bfx, pWfh, bfh, pWe, be,
            hX, cX, hY, cY, start, n);
        iou_kernel<false><<<(n + 7) / 8, 256, 0, stream>>>(
            inputs, pWioux, bioux, pWiouh, biouh,
            hY, cY, hX, cX, start, n);
    }

    out_kernel<<<(B * 2 * HDIM + 255) / 256, 256, 0, stream>>>(hX, cX, out);
}

// Round 14
// 3305.366 us; speedup vs baseline: 1.5016x; 1.2065x over previous
//
#include <hip/hip_runtime.h>
#include <hip/hip_bf16.h>
#include <stdint.h>

#define B 8
#define NN 16383
#define INDIM 300
#define HDIM 512
#define EDIM 100

typedef short bf16x8 __attribute__((ext_vector_type(8)));
typedef float f32x4 __attribute__((ext_vector_type(4)));
typedef unsigned short ushort_t;

__device__ __forceinline__ float sigmoidf_(float v) { return 1.0f / (1.0f + __expf(-v)); }

__device__ __forceinline__ ushort_t f2b(float f) {
    union { float f; unsigned int u; } x; x.f = f;
    unsigned int u = x.u;
    return (ushort_t)((u + 0x7FFFu + ((u >> 16) & 1u)) >> 16);
}
__device__ __forceinline__ float b2f(ushort_t s) {
    union { float f; unsigned int u; } x; x.u = ((unsigned int)s) << 16; return x.f;
}
__device__ __forceinline__ bf16x8 zero8() {
    bf16x8 v;
#pragma unroll
    for (int i = 0; i < 8; ++i) v[i] = 0;
    return v;
}

// packed h/c layout (K=512): elem (R, col) ->
//   (R>>4)*8192 + (col>>5)*512 + ((col>>3)&3)*128 + (R&15)*8 + (col&7)
__device__ __forceinline__ unsigned int pidx(int R, int col) {
    return (unsigned int)((R >> 4) * 8192 + (col >> 5) * 512 + ((col >> 3) & 3) * 128
                          + (R & 15) * 8 + (col & 7));
}

// x-pack level base: tile-granular. lvl 0 (start=0) -> 0; else (start+1)*2560 = 2^lvl*2560.
// Level lvl occupies exactly [2^lvl*2560, 2^(lvl+1)*2560) for lvl>=1; root gets [0,5120).
__device__ __forceinline__ size_t xlvl_base(int start) {
    return start ? (size_t)(start + 1) * 2560 : (size_t)0;
}

// ---------------- pack weights into MFMA B-fragment order.
__global__ __launch_bounds__(256) void pack_kernel(
    const float* __restrict__ W, ushort_t* __restrict__ out,
    int Kdim, int Kt, int total)
{
    int idx = blockIdx.x * 256 + threadIdx.x;
    if (idx >= total) return;
    int lane = idx & 63;
    int kt = (idx >> 6) % Kt;
    int nt = idx / (Kt << 6);
    int n = nt * 16 + (lane & 15);
    int kb = kt * 32 + (lane >> 4) * 8;
    ushort_t v[8];
#pragma unroll
    for (int i = 0; i < 8; ++i) {
        int k = kb + i;
        v[i] = (k < Kdim) ? f2b(W[(size_t)n * Kdim + k]) : (ushort_t)0;
    }
    *reinterpret_cast<uint4*>(out + (size_t)idx * 8) = *reinterpret_cast<const uint4*>(v);
}

// ---------------- pack inputs x into MFMA-A fragment layout, level-local rows.
// R = (g-start)*8+b; elem (R,k) -> xlvl_base(start) + (R>>4)*5120 + (k>>5)*512
//                                  + ((k>>3)&3)*128 + (R&15)*8 + (k&7);  K=320 zero-padded.
__global__ __launch_bounds__(256) void xpack_kernel(
    const float* __restrict__ inputs, ushort_t* __restrict__ xpk)
{
    int tid = blockIdx.x * 256 + threadIdx.x;
    if (tid >= NN * 8 * 40) return;
    int kr = tid & 3;
    int kt = (tid >> 2) % 10;
    int rb = tid / 40;           // g*8 + b
    int g = rb >> 3, b = rb & 7;
    int lvl = 31 - __clz(g + 1);
    int start = (1 << lvl) - 1;
    int R = (g - start) * 8 + b;
    int k0 = kt * 32 + kr * 8;
    ushort_t v[8];
#pragma unroll
    for (int i = 0; i < 8; i += 4) {
        int k = k0 + i;
        float4 xv = make_float4(0.f, 0.f, 0.f, 0.f);
        if (k + 4 <= INDIM)
            xv = *reinterpret_cast<const float4*>(&inputs[((size_t)b * NN + g) * INDIM + k]);
        v[i] = f2b(xv.x); v[i + 1] = f2b(xv.y); v[i + 2] = f2b(xv.z); v[i + 3] = f2b(xv.w);
    }
    size_t o = xlvl_base(start) + (size_t)(R >> 4) * 5120
             + (size_t)kt * 512 + (size_t)kr * 128 + (size_t)(R & 15) * 8;
    *reinterpret_cast<uint4*>(xpk + o) = *reinterpret_cast<const uint4*>(v);
}

// ---------------- children: R8 structure, x A-frags from xpk (no xs LDS). LDS 51.2KB.
__global__ __launch_bounds__(256) void children_kernel(
    const ushort_t* __restrict__ xpk, const float* __restrict__ edge_inputs,
    const ushort_t* __restrict__ pWfx, const float* __restrict__ bfx,
    const ushort_t* __restrict__ pWfh, const float* __restrict__ bfh,
    const ushort_t* __restrict__ pWe,  const float* __restrict__ be,
    const ushort_t* __restrict__ hX, const ushort_t* __restrict__ cX,
    ushort_t* __restrict__ hY, ushort_t* __restrict__ cY,
    int start, int n)
{
    const int nb = blockIdx.x * 4;
    const int t = threadIdx.x;
    const int w = t >> 6, lane = t & 63;
    const int kr = lane >> 4, cl = lane & 15;

    __shared__ ushort_t wc[64][136];    // 17.4 KB
    __shared__ ushort_t epi[64][264];   // 33.8 KB gate-transpose buffer

    // stage wc (rows kid*32 + p*8 + b)
    for (int i = t; i < 64 * 32; i += 256) {
        int r = i >> 5, ch = i & 31;
        int kid = r >> 5, pr = r & 31, p = pr >> 3, b = pr & 7;
        int e = ch * 4;
        ushort_t vv[4] = {0, 0, 0, 0};
        if (e < EDIM && (nb + p) < n) {
            float4 xv = *reinterpret_cast<const float4*>(
                &edge_inputs[((size_t)b * NN + 2 * (start + nb + p) + 1 + kid) * EDIM + e]);
            vv[0] = f2b(xv.x); vv[1] = f2b(xv.y); vv[2] = f2b(xv.z); vv[3] = f2b(xv.w);
        }
        *reinterpret_cast<uint2*>(&wc[r][e]) = *reinterpret_cast<const uint2*>(vv);
    }
    __syncthreads();

    const bf16x8* fWfx = reinterpret_cast<const bf16x8*>(pWfx);
    const bf16x8* fWfh = reinterpret_cast<const bf16x8*>(pWfh);
    const bf16x8* fWe  = reinterpret_cast<const bf16x8*>(pWe);

    // x A-frag base (level packed layout), tiles blockIdx.x*2, +1; row = cl
    const ushort_t* xb = xpk + xlvl_base(start) + (size_t)(blockIdx.x * 2) * 5120 + (size_t)cl * 8;

    // per-lane A-frag offsets for f GEMM (child tile = parent nb+p, row = 8*kid + b)
    unsigned int cbase[4];
#pragma unroll
    for (int mt = 0; mt < 4; ++mt) {
        int kid = mt >> 1, mh = mt & 1;
        int p = 2 * mh + (cl >> 3);
        int b = cl & 7;
        cbase[mt] = ((nb + p) < n)
            ? (unsigned int)((nb + p) * 8192 + (kr * 16 + 8 * kid + b) * 8)
            : 0u;
    }

#pragma unroll 1
    for (int pp = 0; pp < 2; ++pp) {
        const int ntb = w * 8 + pp * 4;

        // ---- xf GEMM (K=320, A from xpk global); bias folded in regs
        f32x4 xfa[4][2];
#pragma unroll
        for (int q = 0; q < 4; ++q)
#pragma unroll
            for (int mh = 0; mh < 2; ++mh)
#pragma unroll
                for (int r = 0; r < 4; ++r) xfa[q][mh][r] = 0.f;
#pragma unroll 2
        for (int kt = 0; kt < 10; ++kt) {
            bf16x8 a0 = *reinterpret_cast<const bf16x8*>(xb + kt * 512 + kr * 128);
            bf16x8 a1 = *reinterpret_cast<const bf16x8*>(xb + 5120 + kt * 512 + kr * 128);
#pragma unroll
            for (int q = 0; q < 4; ++q) {
                bf16x8 bf_ = fWfx[(size_t)((ntb + q) * 10 + kt) * 64 + lane];
                xfa[q][0] = __builtin_amdgcn_mfma_f32_16x16x32_bf16(a0, bf_, xfa[q][0], 0, 0, 0);
                xfa[q][1] = __builtin_amdgcn_mfma_f32_16x16x32_bf16(a1, bf_, xfa[q][1], 0, 0, 0);
            }
        }
#pragma unroll
        for (int q = 0; q < 4; ++q) {
            float bv = bfx[(ntb + q) * 16 + cl];
#pragma unroll
            for (int mh = 0; mh < 2; ++mh)
#pragma unroll
                for (int r = 0; r < 4; ++r) xfa[q][mh][r] += bv;
        }

        // ---- ex GEMM (K=128) -> sigmoid in frag space -> epi
        {
            f32x4 eacc[4][4];
#pragma unroll
            for (int q = 0; q < 4; ++q)
#pragma unroll
                for (int mt = 0; mt < 4; ++mt)
#pragma unroll
                    for (int r = 0; r < 4; ++r) eacc[q][mt][r] = 0.f;
#pragma unroll
            for (int kt = 0; kt < 4; ++kt) {
                bf16x8 av[4];
#pragma unroll
                for (int mt = 0; mt < 4; ++mt)
                    av[mt] = *reinterpret_cast<const bf16x8*>(&wc[mt * 16 + cl][kt * 32 + kr * 8]);
#pragma unroll
                for (int q = 0; q < 4; ++q) {
                    bf16x8 bf_ = fWe[(size_t)((ntb + q) * 4 + kt) * 64 + lane];
#pragma unroll
                    for (int mt = 0; mt < 4; ++mt)
                        eacc[q][mt] = __builtin_amdgcn_mfma_f32_16x16x32_bf16(av[mt], bf_, eacc[q][mt], 0, 0, 0);
                }
            }
#pragma unroll
            for (int q = 0; q < 4; ++q) {
                float bev = be[(ntb + q) * 16 + cl];
#pragma unroll
                for (int mt = 0; mt < 4; ++mt)
#pragma unroll
                    for (int r = 0; r < 4; ++r)
                        epi[mt * 16 + kr * 4 + r][(w * 4 + q) * 16 + cl] =
                            f2b(sigmoidf_(eacc[q][mt][r] + bev));
            }
        }
        __syncthreads();

        // ---- ex apply: hY = ex0*h0 + ex1*h1 (all 16B vector ops)
#pragma unroll 1
        for (int it = 0; it < 4; ++it) {
            int task = it * 256 + t;
            int pb = task >> 5, cb = task & 31;
            int p = pb >> 3, b = pb & 7;
            if (nb + p < n) {
                int lc0 = cb * 8;
                int nt = ((cb >> 3) << 3) + pp * 4 + ((cb >> 1) & 3);
                int hh = cb & 1;
                int colc = (nt >> 1) * 512 + (((nt & 1) << 1) + hh) * 128;
                bf16x8 e0 = *reinterpret_cast<const bf16x8*>(&epi[pb][lc0]);
                bf16x8 e1 = *reinterpret_cast<const bf16x8*>(&epi[32 + pb][lc0]);
                const ushort_t* hb = hX + (unsigned int)((nb + p) * 8192 + colc + b * 8);
                bf16x8 h0 = *reinterpret_cast<const bf16x8*>(hb);
                bf16x8 h1 = *reinterpret_cast<const bf16x8*>(hb + 64);
                ushort_t res[8];
#pragma unroll
                for (int i = 0; i < 8; ++i)
                    res[i] = f2b(b2f((ushort_t)e0[i]) * b2f((ushort_t)h0[i])
                               + b2f((ushort_t)e1[i]) * b2f((ushort_t)h1[i]));
                *reinterpret_cast<uint4*>(hY + (unsigned int)(((nb + p) >> 1) * 8192 + colc
                        + ((((nb + p) & 1) << 3) + b) * 8)) = *reinterpret_cast<const uint4*>(res);
            }
        }
        __syncthreads();

        // ---- f GEMM (K=512, A from packed global) -> sigmoid(+xf) in frag space -> epi
        {
            f32x4 facc[4][4];
#pragma unroll
            for (int q = 0; q < 4; ++q)
#pragma unroll
                for (int mt = 0; mt < 4; ++mt)
#pragma unroll
                    for (int r = 0; r < 4; ++r) facc[q][mt][r] = 0.f;
#pragma unroll 4
            for (int kt = 0; kt < 16; ++kt) {
                bf16x8 av[4];
#pragma unroll
                for (int mt = 0; mt < 4; ++mt)
                    av[mt] = *reinterpret_cast<const bf16x8*>(hX + cbase[mt] + kt * 512u);
#pragma unroll
                for (int q = 0; q < 4; ++q) {
                    bf16x8 bf_ = fWfh[(size_t)((ntb + q) * 16 + kt) * 64 + lane];
#pragma unroll
                    for (int mt = 0; mt < 4; ++mt)
                        facc[q][mt] = __builtin_amdgcn_mfma_f32_16x16x32_bf16(av[mt], bf_, facc[q][mt], 0, 0, 0);
                }
            }
#pragma unroll
            for (int q = 0; q < 4; ++q) {
                float bfhv = bfh[(ntb + q) * 16 + cl];
#pragma unroll
                for (int mt = 0; mt < 4; ++mt)
#pragma unroll
                    for (int r = 0; r < 4; ++r)
                        epi[mt * 16 + kr * 4 + r][(w * 4 + q) * 16 + cl] =
                            f2b(sigmoidf_(facc[q][mt][r] + bfhv + xfa[q][mt & 1][r]));
            }
        }
        __syncthreads();

        // ---- f apply: cY = f0*c0 + f1*c1
#pragma unroll 1
        for (int it = 0; it < 4; ++it) {
            int task = it * 256 + t;
            int pb = task >> 5, cb = task & 31;
            int p = pb >> 3, b = pb & 7;
            if (nb + p < n) {
                int lc0 = cb * 8;
                int nt = ((cb >> 3) << 3) + pp * 4 + ((cb >> 1) & 3);
                int hh = cb & 1;
                int colc = (nt >> 1) * 512 + (((nt & 1) << 1) + hh) * 128;
                bf16x8 f0 = *reinterpret_cast<const bf16x8*>(&epi[pb][lc0]);
                bf16x8 f1 = *reinterpret_cast<const bf16x8*>(&epi[32 + pb][lc0]);
                const ushort_t* cb_ = cX + (unsigned int)((nb + p) * 8192 + colc + b * 8);
                bf16x8 c0 = *reinterpret_cast<const bf16x8*>(cb_);
                bf16x8 c1 = *reinterpret_cast<const bf16x8*>(cb_ + 64);
                ushort_t res[8];
#pragma unroll
                for (int i = 0; i < 8; ++i)
                    res[i] = f2b(b2f((ushort_t)f0[i]) * b2f((ushort_t)c0[i])
                               + b2f((ushort_t)f1[i]) * b2f((ushort_t)c1[i]));
                *reinterpret_cast<uint4*>(cY + (unsigned int)(((nb + p) >> 1) * 8192 + colc
                        + ((((nb + p) & 1) << 3) + b) * 8)) = *reinterpret_cast<const uint4*>(res);
            }
        }
        __syncthreads();
    }
}

// ---------------- iou (also leaf): R8 structure, x from xpk (no xs LDS). LDS 18.6KB.
template <bool LEAF>
__global__ __launch_bounds__(256) void iou_kernel(
    const ushort_t* __restrict__ xpk,
    const ushort_t* __restrict__ pWioux, const float* __restrict__ bioux,
    const ushort_t* __restrict__ pWiouh, const float* __restrict__ biouh,
    const ushort_t* __restrict__ hYsum, const ushort_t* __restrict__ cYfc,
    ushort_t* __restrict__ hOut, ushort_t* __restrict__ cOut,
    int start, int n)
{
    const int nb = blockIdx.x * 8;
    const int t = threadIdx.x;
    const int w = t >> 6, lane = t & 63;
    const int kr = lane >> 4, cl = lane & 15;

    __shared__ ushort_t p1[64][72];     // 9.2 KB  sig(i)*tanh(u)
    __shared__ ushort_t p2[64][72];     // 9.2 KB  sig(o)

    const bf16x8* fWx = reinterpret_cast<const bf16x8*>(pWioux);
    const bf16x8* fWh = reinterpret_cast<const bf16x8*>(pWiouh);

    const ushort_t* xb = xpk + xlvl_base(start) + (size_t)(blockIdx.x * 4) * 5120 + (size_t)cl * 8;

    unsigned int hbase[4];
#pragma unroll
    for (int mt = 0; mt < 4; ++mt)
        hbase[mt] = (unsigned int)(((nb >> 1) + mt) * 8192 + lane * 8);

#pragma unroll 1
    for (int j = 0; j < 8; ++j) {
        const int cnt = j * 4 + w;
        f32x4 acc[4][3];
#pragma unroll
        for (int mt = 0; mt < 4; ++mt)
#pragma unroll
            for (int q = 0; q < 3; ++q)
#pragma unroll
                for (int r = 0; r < 4; ++r) acc[mt][q][r] = 0.f;

#pragma unroll 2
        for (int kt = 0; kt < 10; ++kt) {
            bf16x8 av[4];
#pragma unroll
            for (int mt = 0; mt < 4; ++mt)
                av[mt] = *reinterpret_cast<const bf16x8*>(xb + (size_t)mt * 5120 + kt * 512 + kr * 128);
#pragma unroll
            for (int q = 0; q < 3; ++q) {
                bf16x8 bf_ = fWx[(size_t)((q * 32 + cnt) * 10 + kt) * 64 + lane];
#pragma unroll
                for (int mt = 0; mt < 4; ++mt)
                    acc[mt][q] = __builtin_amdgcn_mfma_f32_16x16x32_bf16(av[mt], bf_, acc[mt][q], 0, 0, 0);
            }
        }
        if (!LEAF) {
#pragma unroll 4
            for (int kt = 0; kt < 16; ++kt) {
                bf16x8 av[4];
#pragma unroll
                for (int mt = 0; mt < 4; ++mt)
                    av[mt] = *reinterpret_cast<const bf16x8*>(hYsum + hbase[mt] + kt * 512u);
#pragma unroll
                for (int q = 0; q < 3; ++q) {
                    bf16x8 bf_ = fWh[(size_t)((q * 32 + cnt) * 16 + kt) * 64 + lane];
#pragma unroll
                    for (int mt = 0; mt < 4; ++mt)
                        acc[mt][q] = __builtin_amdgcn_mfma_f32_16x16x32_bf16(av[mt], bf_, acc[mt][q], 0, 0, 0);
                }
            }
        }

        // frag-space nonlinearities -> P1/P2 planes
        const int col = cnt * 16 + cl;
        const float bi = bioux[col]        + biouh[col];
        const float bo = bioux[col + 512]  + biouh[col + 512];
        const float bu = bioux[col + 1024] + biouh[col + 1024];
#pragma unroll
        for (int mt = 0; mt < 4; ++mt) {
#pragma unroll
            for (int r = 0; r < 4; ++r) {
                int row = mt * 16 + kr * 4 + r;
                float iv = acc[mt][0][r] + bi;
                float ov = acc[mt][1][r] + bo;
                float uv = acc[mt][2][r] + bu;
                p1[row][w * 16 + cl] = f2b(sigmoidf_(iv) * tanhf(uv));
                p2[row][w * 16 + cl] = f2b(sigmoidf_(ov));
            }
        }
        __syncthreads();

        // apply: c = P1 + fc; h = P2 * tanh(c)  (16B vector ops)
#pragma unroll 1
        for (int it = 0; it < 2; ++it) {
            int task = it * 256 + t;
            int rowid = task >> 3, ch = task & 7;
            int p = rowid >> 3, b = rowid & 7;
            if (nb + p < n) {
                int lc0 = ch * 8;
                int c2 = j * 4 + (ch >> 1);
                int hh = ch & 1;
                int colc = (c2 >> 1) * 512 + (((c2 & 1) << 1) + hh) * 128;
                unsigned int o = (unsigned int)(((nb + p) >> 1) * 8192 + colc
                                                + ((((nb + p) & 1) << 3) + b) * 8);
                bf16x8 v1 = *reinterpret_cast<const bf16x8*>(&p1[rowid][lc0]);
                bf16x8 v2 = *reinterpret_cast<const bf16x8*>(&p2[rowid][lc0]);
                bf16x8 vf = zero8();
                if (!LEAF) vf = *reinterpret_cast<const bf16x8*>(cYfc + o);
                ushort_t rh[8], rc[8];
#pragma unroll
                for (int i = 0; i < 8; ++i) {
                    float cv = b2f((ushort_t)v1[i]) + b2f((ushort_t)vf[i]);
                    float hv = b2f((ushort_t)v2[i]) * tanhf(cv);
                    rc[i] = f2b(cv); rh[i] = f2b(hv);
                }
                *reinterpret_cast<uint4*>(cOut + o) = *reinterpret_cast<const uint4*>(rc);
                *reinterpret_cast<uint4*>(hOut + o) = *reinterpret_cast<const uint4*>(rh);
            }
        }
        __syncthreads();
    }
}

// ---------------- output: concat(c_root, h_root) per batch, FP32 (packed-layout read)
__global__ __launch_bounds__(256) void out_kernel(
    const ushort_t* __restrict__ hroot, const ushort_t* __restrict__ croot,
    float* __restrict__ out)
{
    int t = blockIdx.x * 256 + threadIdx.x;
    if (t >= B * 2 * HDIM) return;
    int b = t / (2 * HDIM);
    int j = t - b * 2 * HDIM;
    int col = (j < HDIM) ? j : j - HDIM;
    unsigned int o = pidx(b, col);
    out[t] = (j < HDIM) ? b2f(croot[o]) : b2f(hroot[o]);
}

__global__ void diag_kernel(float* out, float v) { out[0] = v; }

extern "C" void kernel_launch(void* const* d_in, const int* in_sizes, int n_in,
                              void* d_out, int out_size, void* d_ws, size_t ws_size,
                              hipStream_t stream)
{
    const float* inputs      = (const float*)d_in[0];
    const float* edge_inputs = (const float*)d_in[1];
    const float* Wioux       = (const float*)d_in[2];
    const float* bioux       = (const float*)d_in[3];
    const float* Wiouh       = (const float*)d_in[4];
    const float* biouh       = (const float*)d_in[5];
    const float* Wfx         = (const float*)d_in[6];
    const float* bfx         = (const float*)d_in[7];
    const float* Wfh         = (const float*)d_in[8];
    const float* bfh         = (const float*)d_in[9];
    const float* We          = (const float*)d_in[10];
    const float* be          = (const float*)d_in[11];
    float* out = (float*)d_out;

    const size_t szWioux = (size_t)96 * 10 * 64 * 8;
    const size_t szWfx   = (size_t)32 * 10 * 64 * 8;
    const size_t szWe    = (size_t)32 * 4  * 64 * 8;
    const size_t szWfh   = (size_t)32 * 16 * 64 * 8;
    const size_t szWiouh = (size_t)96 * 16 * 64 * 8;

    const size_t eXpk = (size_t)16384 * 2560;         // 41,943,040 (tile-granular levels)
    const size_t eX   = (size_t)B * 8192 * HDIM;      // 33,554,432
    const size_t eY   = (size_t)B * 4096 * HDIM;      // 16,777,216

    const size_t need = (szWioux + szWfx + szWe + szWfh + szWiouh
                         + eXpk + 2 * eX + 2 * eY) * sizeof(ushort_t);  // ~288.7 MB
    if (ws_size < need) {
        diag_kernel<<<1, 1, 0, stream>>>(out, 2.0e8f);
        return;
    }

    ushort_t* p = (ushort_t*)d_ws;
    ushort_t* pWioux = p;            p += szWioux;
    ushort_t* pWfx   = p;            p += szWfx;
    ushort_t* pWe    = p;            p += szWe;
    ushort_t* pWfh   = p;            p += szWfh;
    ushort_t* pWiouh = p;            p += szWiouh;
    ushort_t* xpk = p;               p += eXpk;
    ushort_t* hX = p;                p += eX;
    ushort_t* cX = p;                p += eX;
    ushort_t* hY = p;                p += eY;
    ushort_t* cY = p;                p += eY;

    pack_kernel<<<(96 * 10 * 64 + 255) / 256, 256, 0, stream>>>(Wioux, pWioux, INDIM, 10, 96 * 10 * 64);
    pack_kernel<<<(32 * 10 * 64 + 255) / 256, 256, 0, stream>>>(Wfx,   pWfx,   INDIM, 10, 32 * 10 * 64);
    pack_kernel<<<(32 * 4  * 64 + 255) / 256, 256, 0, stream>>>(We,    pWe,    EDIM,  4,  32 * 4  * 64);
    pack_kernel<<<(32 * 16 * 64 + 255) / 256, 256, 0, stream>>>(Wfh,   pWfh,   HDIM,  16, 32 * 16 * 64);
    pack_kernel<<<(96 * 16 * 64 + 255) / 256, 256, 0, stream>>>(Wiouh, pWiouh, HDIM,  16, 96 * 16 * 64);
    xpack_kernel<<<(NN * 8 * 40 + 255) / 256, 256, 0, stream>>>(inputs, xpk);

    // leaf level: start=8191, n=8192
    iou_kernel<true><<<1024, 256, 0, stream>>>(xpk, pWioux, bioux, pWiouh, biouh,
                                               hY, cY, hX, cX, 8191, 8192);

    for (int lvl = 12; lvl >= 0; --lvl) {
        int start = (1 << lvl) - 1;
        int n = 1 << lvl;
        children_kernel<<<(n + 3) / 4, 256, 0, stream>>>(
            xpk, edge_inputs, pWfx, bfx, pWfh, bfh, pWe, be,
            hX, cX, hY, cY, start, n);
        iou_kernel<false><<<(n + 7) / 8, 256, 0, stream>>>(
            xpk, pWioux, bioux, pWiouh, biouh,
            hY, cY, hX, cX, start, n);
    }

    out_kernel<<<(B * 2 * HDIM + 255) / 256, 256, 0, stream>>>(hX, cX, out);
}

// Round 15
// 1472.804 us; speedup vs baseline: 3.3699x; 2.2443x over previous
//
#include <hip/hip_runtime.h>
#include <hip/hip_bf16.h>
#include <stdint.h>

#define B 8
#define NN 16383
#define INDIM 300
#define HDIM 512
#define EDIM 100

typedef short bf16x8 __attribute__((ext_vector_type(8)));
typedef float f32x4 __attribute__((ext_vector_type(4)));
typedef unsigned short ushort_t;

__device__ __forceinline__ float sigmoidf_(float v) { return 1.0f / (1.0f + __expf(-v)); }

__device__ __forceinline__ ushort_t f2b(float f) {
    union { float f; unsigned int u; } x; x.f = f;
    unsigned int u = x.u;
    return (ushort_t)((u + 0x7FFFu + ((u >> 16) & 1u)) >> 16);
}
__device__ __forceinline__ float b2f(ushort_t s) {
    union { float f; unsigned int u; } x; x.u = ((unsigned int)s) << 16; return x.f;
}
__device__ __forceinline__ bf16x8 zero8() {
    bf16x8 v;
#pragma unroll
    for (int i = 0; i < 8; ++i) v[i] = 0;
    return v;
}

// packed h/c layout (K=512): elem (R, col) ->
//   (R>>4)*8192 + (col>>5)*512 + ((col>>3)&3)*128 + (R&15)*8 + (col&7)
__device__ __forceinline__ unsigned int pidx(int R, int col) {
    return (unsigned int)((R >> 4) * 8192 + (col >> 5) * 512 + ((col >> 3) & 3) * 128
                          + (R & 15) * 8 + (col & 7));
}

// x-pack level base: tile-granular. lvl 0 (start=0) -> 0; else (start+1)*2560.
__device__ __forceinline__ size_t xlvl_base(int start) {
    return start ? (size_t)(start + 1) * 2560 : (size_t)0;
}

// ---------------- pack weights into MFMA B-fragment order.
__global__ __launch_bounds__(256) void pack_kernel(
    const float* __restrict__ W, ushort_t* __restrict__ out,
    int Kdim, int Kt, int total)
{
    int idx = blockIdx.x * 256 + threadIdx.x;
    if (idx >= total) return;
    int lane = idx & 63;
    int kt = (idx >> 6) % Kt;
    int nt = idx / (Kt << 6);
    int n = nt * 16 + (lane & 15);
    int kb = kt * 32 + (lane >> 4) * 8;
    ushort_t v[8];
#pragma unroll
    for (int i = 0; i < 8; ++i) {
        int k = kb + i;
        v[i] = (k < Kdim) ? f2b(W[(size_t)n * Kdim + k]) : (ushort_t)0;
    }
    *reinterpret_cast<uint4*>(out + (size_t)idx * 8) = *reinterpret_cast<const uint4*>(v);
}

// ---------------- pack inputs x into MFMA-A fragment layout, level-local rows.
__global__ __launch_bounds__(256) void xpack_kernel(
    const float* __restrict__ inputs, ushort_t* __restrict__ xpk)
{
    int tid = blockIdx.x * 256 + threadIdx.x;
    if (tid >= NN * 8 * 40) return;
    int kr = tid & 3;
    int kt = (tid >> 2) % 10;
    int rb = tid / 40;           // g*8 + b
    int g = rb >> 3, b = rb & 7;
    int lvl = 31 - __clz(g + 1);
    int start = (1 << lvl) - 1;
    int R = (g - start) * 8 + b;
    int k0 = kt * 32 + kr * 8;
    ushort_t v[8];
#pragma unroll
    for (int i = 0; i < 8; i += 4) {
        int k = k0 + i;
        float4 xv = make_float4(0.f, 0.f, 0.f, 0.f);
        if (k + 4 <= INDIM)
            xv = *reinterpret_cast<const float4*>(&inputs[((size_t)b * NN + g) * INDIM + k]);
        v[i] = f2b(xv.x); v[i + 1] = f2b(xv.y); v[i + 2] = f2b(xv.z); v[i + 3] = f2b(xv.w);
    }
    size_t o = xlvl_base(start) + (size_t)(R >> 4) * 5120
             + (size_t)kt * 512 + (size_t)kr * 128 + (size_t)(R & 15) * 8;
    *reinterpret_cast<uint4*>(xpk + o) = *reinterpret_cast<const uint4*>(v);
}

// ---------------- children: 4 parents/block, pp (column half) = blockIdx.y.
__global__ __launch_bounds__(256) void children_kernel(
    const ushort_t* __restrict__ xpk, const float* __restrict__ edge_inputs,
    const ushort_t* __restrict__ pWfx, const float* __restrict__ bfx,
    const ushort_t* __restrict__ pWfh, const float* __restrict__ bfh,
    const ushort_t* __restrict__ pWe,  const float* __restrict__ be,
    const ushort_t* __restrict__ hX, const ushort_t* __restrict__ cX,
    ushort_t* __restrict__ hY, ushort_t* __restrict__ cY,
    int start, int n)
{
    const int nb = blockIdx.x * 4;
    const int pp = blockIdx.y;
    const int t = threadIdx.x;
    const int w = t >> 6, lane = t & 63;
    const int kr = lane >> 4, cl = lane & 15;

    __shared__ ushort_t wc[64][136];    // 17.4 KB
    __shared__ ushort_t epi[64][264];   // 33.8 KB gate-transpose buffer

    // stage wc (rows kid*32 + p*8 + b)
    for (int i = t; i < 64 * 32; i += 256) {
        int r = i >> 5, ch = i & 31;
        int kid = r >> 5, pr = r & 31, p = pr >> 3, b = pr & 7;
        int e = ch * 4;
        ushort_t vv[4] = {0, 0, 0, 0};
        if (e < EDIM && (nb + p) < n) {
            float4 xv = *reinterpret_cast<const float4*>(
                &edge_inputs[((size_t)b * NN + 2 * (start + nb + p) + 1 + kid) * EDIM + e]);
            vv[0] = f2b(xv.x); vv[1] = f2b(xv.y); vv[2] = f2b(xv.z); vv[3] = f2b(xv.w);
        }
        *reinterpret_cast<uint2*>(&wc[r][e]) = *reinterpret_cast<const uint2*>(vv);
    }
    __syncthreads();

    const bf16x8* fWfx = reinterpret_cast<const bf16x8*>(pWfx);
    const bf16x8* fWfh = reinterpret_cast<const bf16x8*>(pWfh);
    const bf16x8* fWe  = reinterpret_cast<const bf16x8*>(pWe);

    // x A-frag base (level packed layout), tiles blockIdx.x*2, +1; row = cl
    const ushort_t* xb = xpk + xlvl_base(start) + (size_t)(blockIdx.x * 2) * 5120 + (size_t)cl * 8;

    // per-lane A-frag offsets for f GEMM (child tile = parent nb+p, row = 8*kid + b)
    unsigned int cbase[4];
#pragma unroll
    for (int mt = 0; mt < 4; ++mt) {
        int kid = mt >> 1, mh = mt & 1;
        int p = 2 * mh + (cl >> 3);
        int b = cl & 7;
        cbase[mt] = ((nb + p) < n)
            ? (unsigned int)((nb + p) * 8192 + (kr * 16 + 8 * kid + b) * 8)
            : 0u;
    }

    const int ntb = w * 8 + pp * 4;

    // ---- xf GEMM (K=320, A from xpk global); bias folded in regs
    f32x4 xfa[4][2];
#pragma unroll
    for (int q = 0; q < 4; ++q)
#pragma unroll
        for (int mh = 0; mh < 2; ++mh)
#pragma unroll
            for (int r = 0; r < 4; ++r) xfa[q][mh][r] = 0.f;
#pragma unroll 2
    for (int kt = 0; kt < 10; ++kt) {
        bf16x8 a0 = *reinterpret_cast<const bf16x8*>(xb + kt * 512 + kr * 128);
        bf16x8 a1 = *reinterpret_cast<const bf16x8*>(xb + 5120 + kt * 512 + kr * 128);
#pragma unroll
        for (int q = 0; q < 4; ++q) {
            bf16x8 bf_ = fWfx[(size_t)((ntb + q) * 10 + kt) * 64 + lane];
            xfa[q][0] = __builtin_amdgcn_mfma_f32_16x16x32_bf16(a0, bf_, xfa[q][0], 0, 0, 0);
            xfa[q][1] = __builtin_amdgcn_mfma_f32_16x16x32_bf16(a1, bf_, xfa[q][1], 0, 0, 0);
        }
    }
#pragma unroll
    for (int q = 0; q < 4; ++q) {
        float bv = bfx[(ntb + q) * 16 + cl];
#pragma unroll
        for (int mh = 0; mh < 2; ++mh)
#pragma unroll
            for (int r = 0; r < 4; ++r) xfa[q][mh][r] += bv;
    }

    // ---- ex GEMM (K=128) -> sigmoid in frag space -> epi
    {
        f32x4 eacc[4][4];
#pragma unroll
        for (int q = 0; q < 4; ++q)
#pragma unroll
            for (int mt = 0; mt < 4; ++mt)
#pragma unroll
                for (int r = 0; r < 4; ++r) eacc[q][mt][r] = 0.f;
#pragma unroll
        for (int kt = 0; kt < 4; ++kt) {
            bf16x8 av[4];
#pragma unroll
            for (int mt = 0; mt < 4; ++mt)
                av[mt] = *reinterpret_cast<const bf16x8*>(&wc[mt * 16 + cl][kt * 32 + kr * 8]);
#pragma unroll
            for (int q = 0; q < 4; ++q) {
                bf16x8 bf_ = fWe[(size_t)((ntb + q) * 4 + kt) * 64 + lane];
#pragma unroll
                for (int mt = 0; mt < 4; ++mt)
                    eacc[q][mt] = __builtin_amdgcn_mfma_f32_16x16x32_bf16(av[mt], bf_, eacc[q][mt], 0, 0, 0);
            }
        }
#pragma unroll
        for (int q = 0; q < 4; ++q) {
            float bev = be[(ntb + q) * 16 + cl];
#pragma unroll
            for (int mt = 0; mt < 4; ++mt)
#pragma unroll
                for (int r = 0; r < 4; ++r)
                    epi[mt * 16 + kr * 4 + r][(w * 4 + q) * 16 + cl] =
                        f2b(sigmoidf_(eacc[q][mt][r] + bev));
        }
    }
    __syncthreads();

    // ---- ex apply: hY = ex0*h0 + ex1*h1 (all 16B vector ops)
#pragma unroll 1
    for (int it = 0; it < 4; ++it) {
        int task = it * 256 + t;
        int pb = task >> 5, cb = task & 31;
        int p = pb >> 3, b = pb & 7;
        if (nb + p < n) {
            int lc0 = cb * 8;
            int nt = ((cb >> 3) << 3) + pp * 4 + ((cb >> 1) & 3);
            int hh = cb & 1;
            int colc = (nt >> 1) * 512 + (((nt & 1) << 1) + hh) * 128;
            bf16x8 e0 = *reinterpret_cast<const bf16x8*>(&epi[pb][lc0]);
            bf16x8 e1 = *reinterpret_cast<const bf16x8*>(&epi[32 + pb][lc0]);
            const ushort_t* hb = hX + (unsigned int)((nb + p) * 8192 + colc + b * 8);
            bf16x8 h0 = *reinterpret_cast<const bf16x8*>(hb);
            bf16x8 h1 = *reinterpret_cast<const bf16x8*>(hb + 64);
            ushort_t res[8];
#pragma unroll
            for (int i = 0; i < 8; ++i)
                res[i] = f2b(b2f((ushort_t)e0[i]) * b2f((ushort_t)h0[i])
                           + b2f((ushort_t)e1[i]) * b2f((ushort_t)h1[i]));
            *reinterpret_cast<uint4*>(hY + (unsigned int)(((nb + p) >> 1) * 8192 + colc
                    + ((((nb + p) & 1) << 3) + b) * 8)) = *reinterpret_cast<const uint4*>(res);
        }
    }
    __syncthreads();

    // ---- f GEMM (K=512, A from packed global) -> sigmoid(+xf) in frag space -> epi
    {
        f32x4 facc[4][4];
#pragma unroll
        for (int q = 0; q < 4; ++q)
#pragma unroll
            for (int mt = 0; mt < 4; ++mt)
#pragma unroll
                for (int r = 0; r < 4; ++r) facc[q][mt][r] = 0.f;
#pragma unroll 4
        for (int kt = 0; kt < 16; ++kt) {
            bf16x8 av[4];
#pragma unroll
            for (int mt = 0; mt < 4; ++mt)
                av[mt] = *reinterpret_cast<const bf16x8*>(hX + cbase[mt] + kt * 512u);
#pragma unroll
            for (int q = 0; q < 4; ++q) {
                bf16x8 bf_ = fWfh[(size_t)((ntb + q) * 16 + kt) * 64 + lane];
#pragma unroll
                for (int mt = 0; mt < 4; ++mt)
                    facc[q][mt] = __builtin_amdgcn_mfma_f32_16x16x32_bf16(av[mt], bf_, facc[q][mt], 0, 0, 0);
            }
        }
#pragma unroll
        for (int q = 0; q < 4; ++q) {
            float bfhv = bfh[(ntb + q) * 16 + cl];
#pragma unroll
            for (int mt = 0; mt < 4; ++mt)
#pragma unroll
                for (int r = 0; r < 4; ++r)
                    epi[mt * 16 + kr * 4 + r][(w * 4 + q) * 16 + cl] =
                        f2b(sigmoidf_(facc[q][mt][r] + bfhv + xfa[q][mt & 1][r]));
        }
    }
    __syncthreads();

    // ---- f apply: cY = f0*c0 + f1*c1
#pragma unroll 1
    for (int it = 0; it < 4; ++it) {
        int task = it * 256 + t;
        int pb = task >> 5, cb = task & 31;
        int p = pb >> 3, b = pb & 7;
        if (nb + p < n) {
            int lc0 = cb * 8;
            int nt = ((cb >> 3) << 3) + pp * 4 + ((cb >> 1) & 3);
            int hh = cb & 1;
            int colc = (nt >> 1) * 512 + (((nt & 1) << 1) + hh) * 128;
            bf16x8 f0 = *reinterpret_cast<const bf16x8*>(&epi[pb][lc0]);
            bf16x8 f1 = *reinterpret_cast<const bf16x8*>(&epi[32 + pb][lc0]);
            const ushort_t* cb_ = cX + (unsigned int)((nb + p) * 8192 + colc + b * 8);
            bf16x8 c0 = *reinterpret_cast<const bf16x8*>(cb_);
            bf16x8 c1 = *reinterpret_cast<const bf16x8*>(cb_ + 64);
            ushort_t res[8];
#pragma unroll
            for (int i = 0; i < 8; ++i)
                res[i] = f2b(b2f((ushort_t)f0[i]) * b2f((ushort_t)c0[i])
                           + b2f((ushort_t)f1[i]) * b2f((ushort_t)c1[i]));
            *reinterpret_cast<uint4*>(cY + (unsigned int)(((nb + p) >> 1) * 8192 + colc
                    + ((((nb + p) & 1) << 3) + b) * 8)) = *reinterpret_cast<const uint4*>(res);
        }
    }
}

// ---------------- iou (also leaf): 8 parents/block; x staged in LDS (fragment layout);
// JSPAN column tiles per block, j base = blockIdx.y*JSPAN.
template <bool LEAF, int JSPAN>
__global__ __launch_bounds__(256) void iou_kernel(
    const ushort_t* __restrict__ xpk,
    const ushort_t* __restrict__ pWioux, const float* __restrict__ bioux,
    const ushort_t* __restrict__ pWiouh, const float* __restrict__ biouh,
    const ushort_t* __restrict__ hYsum, const ushort_t* __restrict__ cYfc,
    ushort_t* __restrict__ hOut, ushort_t* __restrict__ cOut,
    int start, int n)
{
    const int nb = blockIdx.x * 8;
    const int t = threadIdx.x;
    const int w = t >> 6, lane = t & 63;
    const int kr = lane >> 4, cl = lane & 15;

    __shared__ ushort_t xsl[4 * 5120];  // 40 KB: 4 A-tiles in fragment layout
    __shared__ ushort_t p1[64][72];     // 9.2 KB  sig(i)*tanh(u)
    __shared__ ushort_t p2[64][72];     // 9.2 KB  sig(o)

    // stage x tiles (plain 16B copies; layout already fragment-ordered)
    {
        const ushort_t* xsrc = xpk + xlvl_base(start) + (size_t)(blockIdx.x * 4) * 5120;
        for (int i = t; i < 2560; i += 256)
            *reinterpret_cast<uint4*>(xsl + (size_t)i * 8) =
                *reinterpret_cast<const uint4*>(xsrc + (size_t)i * 8);
    }
    __syncthreads();

    const bf16x8* fWx = reinterpret_cast<const bf16x8*>(pWioux);
    const bf16x8* fWh = reinterpret_cast<const bf16x8*>(pWiouh);

    unsigned int hbase[4];
#pragma unroll
    for (int mt = 0; mt < 4; ++mt)
        hbase[mt] = (unsigned int)(((nb >> 1) + mt) * 8192 + lane * 8);

#pragma unroll 1
    for (int jj = 0; jj < JSPAN; ++jj) {
        const int j = blockIdx.y * JSPAN + jj;
        const int cnt = j * 4 + w;
        f32x4 acc[4][3];
#pragma unroll
        for (int mt = 0; mt < 4; ++mt)
#pragma unroll
            for (int q = 0; q < 3; ++q)
#pragma unroll
                for (int r = 0; r < 4; ++r) acc[mt][q][r] = 0.f;

#pragma unroll 2
        for (int kt = 0; kt < 10; ++kt) {
            bf16x8 av[4];
#pragma unroll
            for (int mt = 0; mt < 4; ++mt)
                av[mt] = *reinterpret_cast<const bf16x8*>(
                    xsl + mt * 5120 + kt * 512 + kr * 128 + cl * 8);
#pragma unroll
            for (int q = 0; q < 3; ++q) {
                bf16x8 bf_ = fWx[(size_t)((q * 32 + cnt) * 10 + kt) * 64 + lane];
#pragma unroll
                for (int mt = 0; mt < 4; ++mt)
                    acc[mt][q] = __builtin_amdgcn_mfma_f32_16x16x32_bf16(av[mt], bf_, acc[mt][q], 0, 0, 0);
            }
        }
        if (!LEAF) {
#pragma unroll 4
            for (int kt = 0; kt < 16; ++kt) {
                bf16x8 av[4];
#pragma unroll
                for (int mt = 0; mt < 4; ++mt)
                    av[mt] = *reinterpret_cast<const bf16x8*>(hYsum + hbase[mt] + kt * 512u);
#pragma unroll
                for (int q = 0; q < 3; ++q) {
                    bf16x8 bf_ = fWh[(size_t)((q * 32 + cnt) * 16 + kt) * 64 + lane];
#pragma unroll
                    for (int mt = 0; mt < 4; ++mt)
                        acc[mt][q] = __builtin_amdgcn_mfma_f32_16x16x32_bf16(av[mt], bf_, acc[mt][q], 0, 0, 0);
                }
            }
        }

        // frag-space nonlinearities -> P1/P2 planes
        const int col = cnt * 16 + cl;
        const float bi = bioux[col]        + biouh[col];
        const float bo = bioux[col + 512]  + biouh[col + 512];
        const float bu = bioux[col + 1024] + biouh[col + 1024];
#pragma unroll
        for (int mt = 0; mt < 4; ++mt) {
#pragma unroll
            for (int r = 0; r < 4; ++r) {
                int row = mt * 16 + kr * 4 + r;
                float iv = acc[mt][0][r] + bi;
                float ov = acc[mt][1][r] + bo;
                float uv = acc[mt][2][r] + bu;
                p1[row][w * 16 + cl] = f2b(sigmoidf_(iv) * tanhf(uv));
                p2[row][w * 16 + cl] = f2b(sigmoidf_(ov));
            }
        }
        __syncthreads();

        // apply: c = P1 + fc; h = P2 * tanh(c)  (16B vector ops)
#pragma unroll 1
        for (int it = 0; it < 2; ++it) {
            int task = it * 256 + t;
            int rowid = task >> 3, ch = task & 7;
            int p = rowid >> 3, b = rowid & 7;
            if (nb + p < n) {
                int lc0 = ch * 8;
                int c2 = j * 4 + (ch >> 1);
                int hh = ch & 1;
                int colc = (c2 >> 1) * 512 + (((c2 & 1) << 1) + hh) * 128;
                unsigned int o = (unsigned int)(((nb + p) >> 1) * 8192 + colc
                                                + ((((nb + p) & 1) << 3) + b) * 8);
                bf16x8 v1 = *reinterpret_cast<const bf16x8*>(&p1[rowid][lc0]);
                bf16x8 v2 = *reinterpret_cast<const bf16x8*>(&p2[rowid][lc0]);
                bf16x8 vf = zero8();
                if (!LEAF) vf = *reinterpret_cast<const bf16x8*>(cYfc + o);
                ushort_t rh[8], rc[8];
#pragma unroll
                for (int i = 0; i < 8; ++i) {
                    float cv = b2f((ushort_t)v1[i]) + b2f((ushort_t)vf[i]);
                    float hv = b2f((ushort_t)v2[i]) * tanhf(cv);
                    rc[i] = f2b(cv); rh[i] = f2b(hv);
                }
                *reinterpret_cast<uint4*>(cOut + o) = *reinterpret_cast<const uint4*>(rc);
                *reinterpret_cast<uint4*>(hOut + o) = *reinterpret_cast<const uint4*>(rh);
            }
        }
        __syncthreads();
    }
}

// ---------------- output: concat(c_root, h_root) per batch, FP32 (packed-layout read)
__global__ __launch_bounds__(256) void out_kernel(
    const ushort_t* __restrict__ hroot, const ushort_t* __restrict__ croot,
    float* __restrict__ out)
{
    int t = blockIdx.x * 256 + threadIdx.x;
    if (t >= B * 2 * HDIM) return;
    int b = t / (2 * HDIM);
    int j = t - b * 2 * HDIM;
    int col = (j < HDIM) ? j : j - HDIM;
    unsigned int o = pidx(b, col);
    out[t] = (j < HDIM) ? b2f(croot[o]) : b2f(hroot[o]);
}

__global__ void diag_kernel(float* out, float v) { out[0] = v; }

extern "C" void kernel_launch(void* const* d_in, const int* in_sizes, int n_in,
                              void* d_out, int out_size, void* d_ws, size_t ws_size,
                              hipStream_t stream)
{
    const float* inputs      = (const float*)d_in[0];
    const float* edge_inputs = (const float*)d_in[1];
    const float* Wioux       = (const float*)d_in[2];
    const float* bioux       = (const float*)d_in[3];
    const float* Wiouh       = (const float*)d_in[4];
    const float* biouh       = (const float*)d_in[5];
    const float* Wfx         = (const float*)d_in[6];
    const float* bfx         = (const float*)d_in[7];
    const float* Wfh         = (const float*)d_in[8];
    const float* bfh         = (const float*)d_in[9];
    const float* We          = (const float*)d_in[10];
    const float* be          = (const float*)d_in[11];
    float* out = (float*)d_out;

    const size_t szWioux = (size_t)96 * 10 * 64 * 8;
    const size_t szWfx   = (size_t)32 * 10 * 64 * 8;
    const size_t szWe    = (size_t)32 * 4  * 64 * 8;
    const size_t szWfh   = (size_t)32 * 16 * 64 * 8;
    const size_t szWiouh = (size_t)96 * 16 * 64 * 8;

    const size_t eXpk = (size_t)16384 * 2560;         // 41,943,040 (tile-granular levels)
    const size_t eX   = (size_t)B * 8192 * HDIM;      // 33,554,432
    const size_t eY   = (size_t)B * 4096 * HDIM;      // 16,777,216

    const size_t need = (szWioux + szWfx + szWe + szWfh + szWiouh
                         + eXpk + 2 * eX + 2 * eY) * sizeof(ushort_t);  // ~288.7 MB
    if (ws_size < need) {
        diag_kernel<<<1, 1, 0, stream>>>(out, 2.0e8f);
        return;
    }

    ushort_t* p = (ushort_t*)d_ws;
    ushort_t* pWioux = p;            p += szWioux;
    ushort_t* pWfx   = p;            p += szWfx;
    ushort_t* pWe    = p;            p += szWe;
    ushort_t* pWfh   = p;            p += szWfh;
    ushort_t* pWiouh = p;            p += szWiouh;
    ushort_t* xpk = p;               p += eXpk;
    ushort_t* hX = p;                p += eX;
    ushort_t* cX = p;                p += eX;
    ushort_t* hY = p;                p += eY;
    ushort_t* cY = p;                p += eY;

    pack_kernel<<<(96 * 10 * 64 + 255) / 256, 256, 0, stream>>>(Wioux, pWioux, INDIM, 10, 96 * 10 * 64);
    pack_kernel<<<(32 * 10 * 64 + 255) / 256, 256, 0, stream>>>(Wfx,   pWfx,   INDIM, 10, 32 * 10 * 64);
    pack_kernel<<<(32 * 4  * 64 + 255) / 256, 256, 0, stream>>>(We,    pWe,    EDIM,  4,  32 * 4  * 64);
    pack_kernel<<<(32 * 16 * 64 + 255) / 256, 256, 0, stream>>>(Wfh,   pWfh,   HDIM,  16, 32 * 16 * 64);
    pack_kernel<<<(96 * 16 * 64 + 255) / 256, 256, 0, stream>>>(Wiouh, pWiouh, HDIM,  16, 96 * 16 * 64);
    xpack_kernel<<<(NN * 8 * 40 + 255) / 256, 256, 0, stream>>>(inputs, xpk);

    // leaf level: start=8191, n=8192
    iou_kernel<true, 8><<<dim3(1024, 1), 256, 0, stream>>>(
        xpk, pWioux, bioux, pWiouh, biouh, hY, cY, hX, cX, 8191, 8192);

    for (int lvl = 12; lvl >= 0; --lvl) {
        int start = (1 << lvl) - 1;
        int n = 1 << lvl;
        children_kernel<<<dim3((n + 3) / 4, 2), 256, 0, stream>>>(
            xpk, edge_inputs, pWfx, bfx, pWfh, bfh, pWe, be,
            hX, cX, hY, cY, start, n);
        if (n >= 2048) {
            iou_kernel<false, 8><<<dim3(n / 8, 1), 256, 0, stream>>>(
                xpk, pWioux, bioux, pWiouh, biouh, hY, cY, hX, cX, start, n);
        } else {
            iou_kernel<false, 1><<<dim3((n + 7) / 8, 8), 256, 0, stream>>>(
                xpk, pWioux, bioux, pWiouh, biouh, hY, cY, hX, cX, start, n);
        }
    }

    out_kernel<<<(B * 2 * HDIM + 255) / 256, 256, 0, stream>>>(hX, cX, out);
}